// Round 18
// baseline (991.380 us; speedup 1.0000x reference)
//
#include <hip/hip_runtime.h>
#include <cstddef>
#include <cstdint>

constexpr int B_ = 8, P_ = 4096, K_ = 20, H_ = 64, C_ = 40;
constexpr int NPT = B_ * P_;
#define NEG_SLOPE 0.2f

typedef unsigned long long u64;
typedef unsigned int u32;
typedef unsigned short u16;
typedef __attribute__((ext_vector_type(8))) short bf16x8;
typedef __attribute__((ext_vector_type(4))) float f32x4;

__device__ inline u16 f2bf(float v) {   // round-to-nearest-even bf16
    u32 bits = __float_as_uint(v);
    return (u16)((bits + 0x7FFFu + ((bits >> 16) & 1)) >> 16);
}
__device__ inline float bf2f(u16 h) { return __uint_as_float((u32)h << 16); }

// sorted-ascending 20-slot bubble insert, f32 keys (positive, bit-ordered)
__device__ __forceinline__ void bubble20f(float (&a)[K_], float key) {
    float carry = key;
#pragma unroll
    for (int s = 0; s < K_; ++s) {
        float as = a[s];
        a[s]  = fminf(carry, as);
        carry = fmaxf(carry, as);
    }
}
// key = (dist_bits & ~0xFFF) | cid   (cid < 4096; dist >= 0 finite)
__device__ __forceinline__ float mkkey(float dist, int cid) {
    return __uint_as_float((__float_as_uint(dist) & 0xFFFFF000u) | (u32)cid);
}

// ---------------------------------------------------------------- fused d2 + h/m split (D=64)
__global__ __launch_bounds__(256) void d2cvt2_kernel(const float* __restrict__ x,
                                                     float* __restrict__ d2,
                                                     u16* __restrict__ xh,
                                                     u16* __restrict__ xm) {
    int i = blockIdx.x * 256 + threadIdx.x;
    if (i >= NPT) return;
    const float* r = x + (size_t)i * 64;
    float s = 0.f;
#pragma unroll
    for (int d8 = 0; d8 < 64; d8 += 8) {
        float4 v0 = *(const float4*)(r + d8);
        float4 v1 = *(const float4*)(r + d8 + 4);
        s += v0.x * v0.x + v0.y * v0.y + v0.z * v0.z + v0.w * v0.w;
        s += v1.x * v1.x + v1.y * v1.y + v1.z * v1.z + v1.w * v1.w;
        float av[8] = {v0.x, v0.y, v0.z, v0.w, v1.x, v1.y, v1.z, v1.w};
        bf16x8 vh, vm;
#pragma unroll
        for (int j = 0; j < 8; ++j) {
            u16 h = f2bf(av[j]);
            float r1 = av[j] - bf2f(h);
            vh[j] = (short)h; vm[j] = (short)f2bf(r1);
        }
        *(bf16x8*)(xh + (size_t)i * 64 + d8) = vh;
        *(bf16x8*)(xm + (size_t)i * 64 + d8) = vm;
    }
    d2[i] = s;
}

// ---------------------------------------------------------------- layer-1 knn (D=3), direct register eval
// Lane layout: lane (q=ln&15, ss=ln>>4); 4 waves x 16 queries/block. d2 computed inline.
__global__ __launch_bounds__(256) void knnf3_kernel(const float* __restrict__ x,
                                                    int* __restrict__ idx) {
    __shared__ float sC[64][4];   // cand x,y,z,d2

    int b = blockIdx.y;
    int q0 = blockIdx.x * 64;
    const float* xc = x + (size_t)b * P_ * 3;

    int t = threadIdx.x, w = t >> 6, ln = t & 63;
    int q  = ln & 15;
    int ss = ln >> 4;

    int qrow = q0 + w * 16 + q;
    float qx = xc[(size_t)qrow * 3];
    float qy = xc[(size_t)qrow * 3 + 1];
    float qz = xc[(size_t)qrow * 3 + 2];
    float qd2 = qx * qx + qy * qy + qz * qz;

    float a[K_];
#pragma unroll
    for (int s = 0; s < K_; ++s)
        a[s] = __uint_as_float(0x7F7FF000u | (u32)s);    // distinct huge finite sentinels
    const float PINV = __uint_as_float(0x7F800000u);     // +inf
    const float BIGF = __uint_as_float(0x7F7FFFFFu);     // FLT_MAX

    float p0 = PINV, p1 = PINV, p2 = PINV, p3 = PINV;
    int pcnt = 0;
    float kthr = BIGF;

    int scc = t >> 2, scm = t & 3;   // staging: one value per thread

#pragma unroll 1
    for (int c0 = 0; c0 < P_; c0 += 64) {
        __syncthreads();   // prev chunk reads done
        if (scm < 3) {
            sC[scc][scm] = xc[(size_t)(c0 + scc) * 3 + scm];
        } else {
            float ax = xc[(size_t)(c0 + scc) * 3];
            float ay = xc[(size_t)(c0 + scc) * 3 + 1];
            float az = xc[(size_t)(c0 + scc) * 3 + 2];
            sC[scc][3] = ax * ax + ay * ay + az * az;
        }
        __syncthreads();   // tile ready

#pragma unroll
        for (int nt = 0; nt < 4; ++nt) {
#pragma unroll
            for (int r = 0; r < 4; ++r) {
                int cl = nt * 16 + ss * 4 + r;
                int cID = c0 + cl;
                float4 cv = *(const float4*)&sC[cl][0];
                float dv = (qd2 + cv.w) - 2.f * (qx * cv.x + qy * cv.y + qz * cv.z);
                if (cID == qrow) dv += 1e10f;
                dv = fmaxf(dv, 0.f);
                if (__any(dv <= kthr)) {
                    float key = mkkey(dv, cID);
                    bool pass = key < a[K_ - 1];
                    p3 = pass ? p2 : p3;
                    p2 = pass ? p1 : p2;
                    p1 = pass ? p0 : p1;
                    p0 = pass ? key : p0;
                    pcnt = pass ? pcnt + 1 : pcnt;
                    if (__any(pcnt >= 4)) {
                        bubble20f(a, p3); bubble20f(a, p2); bubble20f(a, p1); bubble20f(a, p0);
                        p0 = p1 = p2 = p3 = PINV; pcnt = 0;
                        kthr = __uint_as_float(__float_as_uint(a[K_ - 1]) | 0xFFFu);
                    }
                }
            }
        }
    }
    bubble20f(a, p3); bubble20f(a, p2); bubble20f(a, p1); bubble20f(a, p0);

    int* op = idx + ((size_t)(b * P_ + qrow)) * K_;
#pragma unroll 1
    for (int k = 0; k < K_; ++k) {
        float v = a[0];
        float v1 = __shfl_xor(v, 16);
        v = fminf(v, v1);
        float v2 = __shfl_xor(v, 32);
        v = fminf(v, v2);
        bool win = (__float_as_uint(a[0]) == __float_as_uint(v));
#pragma unroll
        for (int s = 0; s < K_ - 1; ++s) a[s] = win ? a[s + 1] : a[s];
        a[K_ - 1] = win ? BIGF : a[K_ - 1];
        if (ss == 0)
            op[k] = b * P_ + (int)(__float_as_uint(v) & 0xFFFu);
    }
}

// ---------------------------------------------------------------- fused knn (D=64) via MFMA, 3-product h/m
// Per-chunk cd2 staging (no full-P d2 stage); qd2 from global.
__global__ __launch_bounds__(256) void knnm64_kernel(const u16* __restrict__ xh,
                                                     const u16* __restrict__ xm,
                                                     const float* __restrict__ d2,
                                                     int* __restrict__ idx) {
    __shared__ u16 sH[64 * 64];      // elem (r,k) at byte r*128 + ((k*2) ^ ((r&7)<<4))
    __shared__ u16 sM[64 * 64];
    __shared__ float sCd2[64];

    int b = blockIdx.y;
    int q0 = blockIdx.x * 64;
    const u16* xhb = xh + (size_t)b * P_ * 64;
    const u16* xmb = xm + (size_t)b * P_ * 64;
    const float* d2b = d2 + (size_t)b * P_;

    int t = threadIdx.x, w = t >> 6, ln = t & 63;
    int q  = ln & 15;
    int ss = ln >> 4;

    int qrow = q0 + w * 16 + q;
    bf16x8 qh[2], qm[2];
#pragma unroll
    for (int kt = 0; kt < 2; ++kt) {
        size_t off = (size_t)qrow * 64 + kt * 32 + ss * 8;
        qh[kt] = *(const bf16x8*)(xhb + off);
        qm[kt] = *(const bf16x8*)(xmb + off);
    }
    float qd2 = d2b[qrow];

    float a[K_];
#pragma unroll
    for (int s = 0; s < K_; ++s)
        a[s] = __uint_as_float(0x7F7FF000u | (u32)s);
    const float PINV = __uint_as_float(0x7F800000u);     // +inf
    const float BIGF = __uint_as_float(0x7F7FFFFFu);     // FLT_MAX

    float p0 = PINV, p1 = PINV, p2 = PINV, p3 = PINV;
    int pcnt = 0;
    float kthr = BIGF;

    int sr = t >> 2;
    int sk2 = (t & 3) * 32;
    int sbase = sr * 128, sswz = (sr & 7) << 4;
    size_t sgof = (size_t)sr * 64 + (t & 3) * 16;

#pragma unroll 1
    for (int c0 = 0; c0 < P_; c0 += 64) {
        __syncthreads();
        {
            size_t g = (size_t)c0 * 64 + sgof;
            bf16x8 h0 = *(const bf16x8*)(xhb + g);
            bf16x8 h1 = *(const bf16x8*)(xhb + g + 8);
            bf16x8 m0 = *(const bf16x8*)(xmb + g);
            bf16x8 m1 = *(const bf16x8*)(xmb + g + 8);
            *(bf16x8*)((char*)sH + sbase + (sk2 ^ sswz)) = h0;
            *(bf16x8*)((char*)sH + sbase + ((sk2 + 16) ^ sswz)) = h1;
            *(bf16x8*)((char*)sM + sbase + (sk2 ^ sswz)) = m0;
            *(bf16x8*)((char*)sM + sbase + ((sk2 + 16) ^ sswz)) = m1;
            if (t < 64) sCd2[t] = d2b[c0 + t];
        }
        __syncthreads();

        f32x4 acc[4];
#pragma unroll
        for (int nt = 0; nt < 4; ++nt) {
            acc[nt] = (f32x4){0.f, 0.f, 0.f, 0.f};
            int r = nt * 16 + q;
            int base = r * 128, swz = (r & 7) << 4;
#pragma unroll
            for (int kt = 0; kt < 2; ++kt) {
                int k2 = kt * 64 + ss * 16;
                bf16x8 ch = *(const bf16x8*)((char*)sH + base + (k2 ^ swz));
                bf16x8 cm = *(const bf16x8*)((char*)sM + base + (k2 ^ swz));
                // 3-product split: hh + hm + mh
                acc[nt] = __builtin_amdgcn_mfma_f32_16x16x32_bf16(cm, qh[kt], acc[nt], 0, 0, 0);
                acc[nt] = __builtin_amdgcn_mfma_f32_16x16x32_bf16(ch, qm[kt], acc[nt], 0, 0, 0);
                acc[nt] = __builtin_amdgcn_mfma_f32_16x16x32_bf16(ch, qh[kt], acc[nt], 0, 0, 0);
            }
        }

        float dvv[4][4];
        float mn = 3.4e38f;
#pragma unroll
        for (int nt = 0; nt < 4; ++nt) {
#pragma unroll
            for (int r = 0; r < 4; ++r) {
                int cl = nt * 16 + ss * 4 + r;
                float dv = (qd2 + sCd2[cl]) - 2.f * acc[nt][r];
                if (c0 + cl == qrow) dv += 1e10f;
                dv = fmaxf(dv, 0.f);
                dvv[nt][r] = dv;
                mn = fminf(mn, dv);
            }
        }
        if (__any(mn <= kthr)) {
#pragma unroll
            for (int nt = 0; nt < 4; ++nt) {
#pragma unroll
                for (int r = 0; r < 4; ++r) {
                    float dv = dvv[nt][r];
                    if (__any(dv <= kthr)) {
                        float key = mkkey(dv, c0 + nt * 16 + ss * 4 + r);
                        bool pass = key < a[K_ - 1];
                        p3 = pass ? p2 : p3;
                        p2 = pass ? p1 : p2;
                        p1 = pass ? p0 : p1;
                        p0 = pass ? key : p0;
                        pcnt = pass ? pcnt + 1 : pcnt;
                        if (__any(pcnt >= 4)) {
                            bubble20f(a, p3); bubble20f(a, p2); bubble20f(a, p1); bubble20f(a, p0);
                            p0 = p1 = p2 = p3 = PINV; pcnt = 0;
                            kthr = __uint_as_float(__float_as_uint(a[K_ - 1]) | 0xFFFu);
                        }
                    }
                }
            }
        }
    }
    bubble20f(a, p3); bubble20f(a, p2); bubble20f(a, p1); bubble20f(a, p0);

    int* op = idx + ((size_t)(b * P_ + qrow)) * K_;
#pragma unroll 1
    for (int k = 0; k < K_; ++k) {
        float v = a[0];
        float v1 = __shfl_xor(v, 16);
        v = fminf(v, v1);
        float v2 = __shfl_xor(v, 32);
        v = fminf(v, v2);
        bool win = (__float_as_uint(a[0]) == __float_as_uint(v));
#pragma unroll
        for (int s = 0; s < K_ - 1; ++s) a[s] = win ? a[s + 1] : a[s];
        a[K_ - 1] = win ? BIGF : a[K_ - 1];
        if (ss == 0)
            op[k] = b * P_ + (int)(__float_as_uint(v) & 0xFFFu);
    }
}

// ---------------------------------------------------------------- one-shot weight prep
__global__ __launch_bounds__(256) void prep_kernel(const float* __restrict__ W2,
                                                   const float* __restrict__ b2,
                                                   const float* __restrict__ W3,
                                                   const float* __restrict__ b3,
                                                   const float* __restrict__ Wl,
                                                   const float* __restrict__ Wm1,
                                                   const float* __restrict__ Wm2,
                                                   float* __restrict__ Wpk2, float* __restrict__ bpk2,
                                                   float* __restrict__ Wpk3, float* __restrict__ bpk3,
                                                   u16* __restrict__ WlT,
                                                   u16* __restrict__ Wm1T,
                                                   u16* __restrict__ Wm2T) {
    int t = blockIdx.x * 256 + threadIdx.x;
    if (t < 8192) {
        int d = t >> 7, h2 = t & 127;
        Wpk2[t] = (h2 < 64) ? W2[d * 64 + h2] : W2[(64 + d) * 64 + (h2 - 64)];
        if (t < 128) bpk2[t] = (t < 64) ? b2[t] : 0.f;
    } else if (t < 16384) {
        int t2 = t - 8192;
        int d = t2 >> 7, h2 = t2 & 127;
        Wpk3[t2] = (h2 < 64) ? W3[d * 64 + h2] : W3[(64 + d) * 64 + (h2 - 64)];
        if (t2 < 128) bpk3[t2] = (t2 < 64) ? b3[t2] : 0.f;
    } else if (t < 212992) {
        int t2 = t - 16384;
        int k = t2 >> 10, n = t2 & 1023;
        WlT[(size_t)n * 192 + k] = f2bf(Wl[t2]);
    } else if (t < 475136) {
        int t2 = t - 212992;
        int k = t2 >> 8, n = t2 & 255;
        Wm1T[(size_t)n * 1024 + k] = f2bf(Wm1[t2]);
    } else if (t < 507904) {
        int t2 = t - 475136;
        int k = t2 >> 7, n = t2 & 127;
        Wm2T[(size_t)n * 256 + k] = f2bf(Wm2[t2]);
    }
}

// ---------------------------------------------------------------- layer-1 UV (D=3, direct)
__global__ __launch_bounds__(256) void uv3_kernel(const float* __restrict__ x,
                                                  const float* __restrict__ W,
                                                  const float* __restrict__ b,
                                                  float* __restrict__ UV) {
    int t = blockIdx.x * 256 + threadIdx.x;
    int p = t >> 7, h2 = t & 127;
    float x0 = x[p * 3], x1 = x[p * 3 + 1], x2 = x[p * 3 + 2];
    float r;
    if (h2 < 64) {
        r = b[h2] + x0 * W[h2] + x1 * W[64 + h2] + x2 * W[128 + h2];
    } else {
        int h = h2 - 64;
        r = x0 * W[192 + h] + x1 * W[256 + h] + x2 * W[320 + h];
    }
    UV[t] = r;
}

// ---------------------------------------------------------------- edge max
__global__ __launch_bounds__(256) void edgemax_kernel(const float* __restrict__ UV,
                                                      const int* __restrict__ idx,
                                                      float* __restrict__ xout) {
    int wv = threadIdx.x >> 6, lane = threadIdx.x & 63;
    int p = blockIdx.x * 4 + wv;
    const float* uvp = UV + (size_t)p * 128;
    float duv = uvp[lane] - uvp[64 + lane];
    const int* ip = idx + (size_t)p * K_;
    int jj[K_];
#pragma unroll
    for (int k = 0; k < K_; ++k) jj[k] = ip[k];
    float m = -3.4e38f;
#pragma unroll
    for (int k = 0; k < K_; ++k) {
        float vj = UV[(size_t)jj[k] * 128 + 64 + lane];
        float t = duv + vj;
        m = fmaxf(m, fmaxf(t, NEG_SLOPE * t));
    }
    xout[(size_t)p * H_ + lane] = m;
}

// ---------------------------------------------------------------- GEMM 64x64 f32 (UV)
__global__ __launch_bounds__(256) void gemm_kernel(const float* __restrict__ A1,
                                                   const float* __restrict__ Wm,
                                                   const float* __restrict__ bias,
                                                   float* __restrict__ Cm,
                                                   int M, int N, int Kd, int leaky) {
    __shared__ float sA[32][68];
    __shared__ float sB[32][68];

    int tid = threadIdx.x;
    int row0 = blockIdx.x * 64, col0 = blockIdx.y * 64;
    int tx = tid & 15, ty = tid >> 4;

    int lr  = tid >> 2;
    int lk4 = (tid & 3) * 4;
    int lkb = tid >> 4;
    int lnb = (tid & 15) * 4;

    float acc[4][4] = {};

    for (int k0 = 0; k0 < Kd; k0 += 32) {
        int arow = row0 + lr;
#pragma unroll
        for (int h = 0; h < 32; h += 16) {
            int kk = k0 + lk4 + h;
            const float* src = A1 + (size_t)arow * Kd + kk;
            float4 av = *(const float4*)src;
            sA[lk4 + h + 0][lr] = av.x; sA[lk4 + h + 1][lr] = av.y;
            sA[lk4 + h + 2][lr] = av.z; sA[lk4 + h + 3][lr] = av.w;
        }
        int bcol = col0 + lnb;
#pragma unroll
        for (int h = 0; h < 32; h += 16) {
            float4 bv = make_float4(0.f, 0.f, 0.f, 0.f);
            if (bcol < N) bv = *(const float4*)(Wm + (size_t)(k0 + lkb + h) * N + bcol);
            *(float4*)&sB[lkb + h][lnb] = bv;
        }
        __syncthreads();

#pragma unroll
        for (int kk2 = 0; kk2 < 32; ++kk2) {
            float4 a = *(const float4*)&sA[kk2][ty * 4];
            float4 bb = *(const float4*)&sB[kk2][tx * 4];
            acc[0][0] = fmaf(a.x, bb.x, acc[0][0]); acc[0][1] = fmaf(a.x, bb.y, acc[0][1]);
            acc[0][2] = fmaf(a.x, bb.z, acc[0][2]); acc[0][3] = fmaf(a.x, bb.w, acc[0][3]);
            acc[1][0] = fmaf(a.y, bb.x, acc[1][0]); acc[1][1] = fmaf(a.y, bb.y, acc[1][1]);
            acc[1][2] = fmaf(a.y, bb.z, acc[1][2]); acc[1][3] = fmaf(a.y, bb.w, acc[1][3]);
            acc[2][0] = fmaf(a.z, bb.x, acc[2][0]); acc[2][1] = fmaf(a.z, bb.y, acc[2][1]);
            acc[2][2] = fmaf(a.z, bb.z, acc[2][2]); acc[2][3] = fmaf(a.z, bb.w, acc[2][3]);
            acc[3][0] = fmaf(a.w, bb.x, acc[3][0]); acc[3][1] = fmaf(a.w, bb.y, acc[3][1]);
            acc[3][2] = fmaf(a.w, bb.z, acc[3][2]); acc[3][3] = fmaf(a.w, bb.w, acc[3][3]);
        }
        __syncthreads();
    }

    for (int i = 0; i < 4; ++i) {
        int row = row0 + ty * 4 + i;
        for (int j = 0; j < 4; ++j) {
            int col = col0 + tx * 4 + j;
            if (col < N) {
                float v = acc[i][j] + bias[col];
                if (leaky) v = v > 0.f ? v : NEG_SLOPE * v;
                Cm[(size_t)row * N + col] = v;
            }
        }
    }
}

// ---------------------------------------------------------------- MFMA GEMM head (bf16 A)
template <int KD, int OUT_BF16>
__global__ __launch_bounds__(256) void gemm_mfma_kernel(const u16* __restrict__ A,
                                                        const u16* __restrict__ BT,
                                                        const float* __restrict__ bias,
                                                        void* __restrict__ Cout,
                                                        int N, int leaky) {
    __shared__ u16 sA[128 * 64];
    __shared__ u16 sB[128 * 64];

    int t = threadIdx.x;
    int wave = t >> 6, lane = t & 63;
    int wm = wave >> 1, wn = wave & 1;
    int row0 = blockIdx.x * 128;
    int col0 = blockIdx.y * 128;

    f32x4 acc[4][4] = {};

    for (int k0 = 0; k0 < KD; k0 += 64) {
        __syncthreads();
#pragma unroll
        for (int i = 0; i < 4; ++i) {
            int li = t + i * 256;
            int r = li >> 3;
            int kc = (li & 7) * 8;
            bf16x8 v = *(const bf16x8*)(A + (size_t)(row0 + r) * KD + k0 + kc);
            *(bf16x8*)((char*)sA + r * 128 + ((kc * 2) ^ ((r & 7) << 4))) = v;
        }
#pragma unroll
        for (int i = 0; i < 4; ++i) {
            int li = t + i * 256;
            int n = li >> 3;
            int kc = (li & 7) * 8;
            bf16x8 v = *(const bf16x8*)(BT + (size_t)(col0 + n) * KD + k0 + kc);
            *(bf16x8*)((char*)sB + n * 128 + ((kc * 2) ^ ((n & 7) << 4))) = v;
        }
        __syncthreads();

#pragma unroll
        for (int kk = 0; kk < 2; ++kk) {
            int kb = kk * 64 + (lane >> 4) * 16;
            bf16x8 af[4], bfr[4];
#pragma unroll
            for (int mi = 0; mi < 4; ++mi) {
                int r = wm * 64 + mi * 16 + (lane & 15);
                af[mi] = *(const bf16x8*)((char*)sA + r * 128 + (kb ^ ((r & 7) << 4)));
            }
#pragma unroll
            for (int ni = 0; ni < 4; ++ni) {
                int n = wn * 64 + ni * 16 + (lane & 15);
                bfr[ni] = *(const bf16x8*)((char*)sB + n * 128 + (kb ^ ((n & 7) << 4)));
            }
#pragma unroll
            for (int mi = 0; mi < 4; ++mi)
#pragma unroll
                for (int ni = 0; ni < 4; ++ni)
                    acc[mi][ni] = __builtin_amdgcn_mfma_f32_16x16x32_bf16(
                        af[mi], bfr[ni], acc[mi][ni], 0, 0, 0);
        }
    }

#pragma unroll
    for (int ni = 0; ni < 4; ++ni) {
        int col = col0 + wn * 64 + ni * 16 + (lane & 15);
        float bs = bias[col];
#pragma unroll
        for (int mi = 0; mi < 4; ++mi) {
#pragma unroll
            for (int r = 0; r < 4; ++r) {
                int row = row0 + wm * 64 + mi * 16 + (lane >> 4) * 4 + r;
                float v = acc[mi][ni][r] + bs;
                if (leaky) v = v > 0.f ? v : NEG_SLOPE * v;
                if (OUT_BF16)
                    ((u16*)Cout)[(size_t)row * N + col] = f2bf(v);
                else
                    ((float*)Cout)[(size_t)row * N + col] = v;
            }
        }
    }
}

// ---------------------------------------------------------------- MFMA GEMM, cat-f32 A (fused cvt)
__global__ __launch_bounds__(256) void gemm_mfma_cat_kernel(const float* __restrict__ x1,
                                                            const float* __restrict__ x2,
                                                            const float* __restrict__ x3,
                                                            const u16* __restrict__ BT,
                                                            const float* __restrict__ bias,
                                                            u16* __restrict__ Cout,
                                                            int N) {
    __shared__ u16 sA[128 * 64];
    __shared__ u16 sB[128 * 64];

    int t = threadIdx.x;
    int wave = t >> 6, lane = t & 63;
    int wm = wave >> 1, wn = wave & 1;
    int row0 = blockIdx.x * 128;
    int col0 = blockIdx.y * 128;

    f32x4 acc[4][4] = {};

#pragma unroll 1
    for (int k0 = 0; k0 < 192; k0 += 64) {
        const float* src = (k0 == 0) ? x1 : (k0 == 64) ? x2 : x3;
        __syncthreads();
#pragma unroll
        for (int i = 0; i < 4; ++i) {
            int li = t + i * 256;
            int r = li >> 3;
            int kc = (li & 7) * 8;
            const float* sp = src + (size_t)(row0 + r) * 64 + kc;
            float4 a0 = *(const float4*)sp;
            float4 a1 = *(const float4*)(sp + 4);
            bf16x8 v;
            v[0] = (short)f2bf(a0.x); v[1] = (short)f2bf(a0.y);
            v[2] = (short)f2bf(a0.z); v[3] = (short)f2bf(a0.w);
            v[4] = (short)f2bf(a1.x); v[5] = (short)f2bf(a1.y);
            v[6] = (short)f2bf(a1.z); v[7] = (short)f2bf(a1.w);
            *(bf16x8*)((char*)sA + r * 128 + ((kc * 2) ^ ((r & 7) << 4))) = v;
        }
#pragma unroll
        for (int i = 0; i < 4; ++i) {
            int li = t + i * 256;
            int n = li >> 3;
            int kc = (li & 7) * 8;
            bf16x8 v = *(const bf16x8*)(BT + (size_t)(col0 + n) * 192 + k0 + kc);
            *(bf16x8*)((char*)sB + n * 128 + ((kc * 2) ^ ((n & 7) << 4))) = v;
        }
        __syncthreads();

#pragma unroll
        for (int kk = 0; kk < 2; ++kk) {
            int kb = kk * 64 + (lane >> 4) * 16;
            bf16x8 af[4], bfr[4];
#pragma unroll
            for (int mi = 0; mi < 4; ++mi) {
                int r = wm * 64 + mi * 16 + (lane & 15);
                af[mi] = *(const bf16x8*)((char*)sA + r * 128 + (kb ^ ((r & 7) << 4)));
            }
#pragma unroll
            for (int ni = 0; ni < 4; ++ni) {
                int n = wn * 64 + ni * 16 + (lane & 15);
                bfr[ni] = *(const bf16x8*)((char*)sB + n * 128 + (kb ^ ((n & 7) << 4)));
            }
#pragma unroll
            for (int mi = 0; mi < 4; ++mi)
#pragma unroll
                for (int ni = 0; ni < 4; ++ni)
                    acc[mi][ni] = __builtin_amdgcn_mfma_f32_16x16x32_bf16(
                        af[mi], bfr[ni], acc[mi][ni], 0, 0, 0);
        }
    }

#pragma unroll
    for (int ni = 0; ni < 4; ++ni) {
        int col = col0 + wn * 64 + ni * 16 + (lane & 15);
        float bs = bias[col];
#pragma unroll
        for (int mi = 0; mi < 4; ++mi) {
#pragma unroll
            for (int r = 0; r < 4; ++r) {
                int row = row0 + wm * 64 + mi * 16 + (lane >> 4) * 4 + r;
                float v = acc[mi][ni][r] + bs;
                v = v > 0.f ? v : NEG_SLOPE * v;
                Cout[(size_t)row * N + col] = f2bf(v);
            }
        }
    }
}

// ---------------------------------------------------------------- fused tail: act3 = leaky(act2@Wm2T+bm2) in LDS,
// then out = log_softmax(act3 @ Wo + bo). 64-row tiles.
__global__ __launch_bounds__(256) void tail_kernel(const u16* __restrict__ act2,
                                                   const u16* __restrict__ Wm2T,
                                                   const float* __restrict__ bm2,
                                                   const float* __restrict__ Wo,
                                                   const float* __restrict__ bo,
                                                   float* __restrict__ out) {
    __shared__ float sAct[64][132];   // 33.8 KB
    __shared__ float sWo[128 * 44];   // 22.5 KB

    int t = threadIdx.x, w = t >> 6, lane = t & 63;
    int row0 = blockIdx.x * 64;

    for (int i = t; i < 128 * 40; i += 256) {
        int k = i / 40, c = i % 40;
        sWo[k * 44 + c] = Wo[i];
    }

    // GEMM phase: wave w owns rows row0+w*16 .. +15; cols 0..127; K=256
    int arow = row0 + w * 16 + (lane & 15);
    bf16x8 af[8];
#pragma unroll
    for (int kt = 0; kt < 8; ++kt)
        af[kt] = *(const bf16x8*)(act2 + (size_t)arow * 256 + kt * 32 + (lane >> 4) * 8);

#pragma unroll
    for (int ni = 0; ni < 8; ++ni) {
        f32x4 acc = (f32x4){0.f, 0.f, 0.f, 0.f};
        int n = ni * 16 + (lane & 15);
#pragma unroll
        for (int kt = 0; kt < 8; ++kt) {
            bf16x8 bf = *(const bf16x8*)(Wm2T + (size_t)n * 256 + kt * 32 + (lane >> 4) * 8);
            acc = __builtin_amdgcn_mfma_f32_16x16x32_bf16(af[kt], bf, acc, 0, 0, 0);
        }
        float bs = bm2[n];
#pragma unroll
        for (int r = 0; r < 4; ++r) {
            float v = acc[r] + bs;
            v = v > 0.f ? v : NEG_SLOPE * v;
            sAct[w * 16 + (lane >> 4) * 4 + r][n] = v;
        }
    }
    __syncthreads();

    // Wo GEMV + log_softmax: wave w handles its 16 rows
#pragma unroll 1
    for (int rr = 0; rr < 16; ++rr) {
        int lrow = w * 16 + rr;
        float accv = (lane < C_) ? bo[lane] : -3.4e38f;
        if (lane < C_) {
#pragma unroll 8
            for (int k = 0; k < 128; ++k)
                accv = fmaf(sAct[lrow][k], sWo[k * 44 + lane], accv);
        }
        float m = accv;
#pragma unroll
        for (int s = 1; s < 64; s <<= 1) m = fmaxf(m, __shfl_xor(m, s));
        float e = (lane < C_) ? expf(accv - m) : 0.f;
        float sum = e;
#pragma unroll
        for (int s = 1; s < 64; s <<= 1) sum += __shfl_xor(sum, s);
        if (lane < C_) out[(size_t)(row0 + lrow) * C_ + lane] = accv - m - logf(sum);
    }
}

// ----------------------------------------------------------------
extern "C" void kernel_launch(void* const* d_in, const int* in_sizes, int n_in,
                              void* d_out, int out_size, void* d_ws, size_t ws_size,
                              hipStream_t stream) {
    const float* x   = (const float*)d_in[0];
    const float* W1  = (const float*)d_in[2];
    const float* b1  = (const float*)d_in[3];
    const float* W2  = (const float*)d_in[4];
    const float* b2  = (const float*)d_in[5];
    const float* W3  = (const float*)d_in[6];
    const float* b3  = (const float*)d_in[7];
    const float* Wl  = (const float*)d_in[8];
    const float* bl  = (const float*)d_in[9];
    const float* Wm1 = (const float*)d_in[10];
    const float* bm1 = (const float*)d_in[11];
    const float* Wm2 = (const float*)d_in[12];
    const float* bm2 = (const float*)d_in[13];
    const float* Wo  = (const float*)d_in[14];
    const float* bo  = (const float*)d_in[15];
    float* out = (float*)d_out;

    // ---- workspace (max 50,987,008 B — proven footprint) ----
    char* ws = (char*)d_ws;
    float* x1   = (float*)(ws);
    float* x2   = (float*)(ws + 8388608);
    float* x3   = (float*)(ws + 16777216);
    int*   idx  = (int*)  (ws + 25165824);
    float* d2   = (float*)(ws + 27787264);
    char* hb = ws + 27918336;
    u16*   xhs  = (u16*)(hb);                         // 4 MB
    u16*   xms  = (u16*)(hb + 4194304);               // 4 MB
    float* UV   = (float*)(hb);                       // 16 MB
    float* Wpk2 = (float*)(ws + 44695552);
    float* bpk2 = (float*)(ws + 44728320);
    float* Wpk3 = (float*)(ws + 44728832);
    float* bpk3 = (float*)(ws + 44761600);
    u16*   WlT  = (u16*)  (ws + 44762112);
    u16*   Wm1T = (u16*)  (ws + 45155328);
    u16*   Wm2T = (u16*)  (ws + 45679616);
    u16*   act1 = (u16*)(hb);
    u16*   act2 = (u16*)(ws + 45745152);

    prep_kernel<<<1984, 256, 0, stream>>>(W2, b2, W3, b3, Wl, Wm1, Wm2,
                                          Wpk2, bpk2, Wpk3, bpk3, WlT, Wm1T, Wm2T);

    // ---- layer 1 (D=3)
    knnf3_kernel<<<dim3(P_ / 64, B_), 256, 0, stream>>>(x, idx);
    uv3_kernel<<<NPT * 128 / 256, 256, 0, stream>>>(x, W1, b1, UV);
    edgemax_kernel<<<NPT / 4, 256, 0, stream>>>(UV, idx, x1);
    // ---- layer 2 (D=64)
    d2cvt2_kernel<<<NPT / 256, 256, 0, stream>>>(x1, d2, xhs, xms);
    knnm64_kernel<<<dim3(P_ / 64, B_), 256, 0, stream>>>(xhs, xms, d2, idx);
    gemm_kernel<<<dim3(NPT / 64, 2), 256, 0, stream>>>(x1, Wpk2, bpk2, UV, NPT, 128, 64, 0);
    edgemax_kernel<<<NPT / 4, 256, 0, stream>>>(UV, idx, x2);
    // ---- layer 3 (D=64)
    d2cvt2_kernel<<<NPT / 256, 256, 0, stream>>>(x2, d2, xhs, xms);
    knnm64_kernel<<<dim3(P_ / 64, B_), 256, 0, stream>>>(xhs, xms, d2, idx);
    gemm_kernel<<<dim3(NPT / 64, 2), 256, 0, stream>>>(x2, Wpk3, bpk3, UV, NPT, 128, 64, 0);
    edgemax_kernel<<<NPT / 4, 256, 0, stream>>>(UV, idx, x3);

    // ---- MLP head: 4 chunks of 8192 rows
    for (int c = 0; c < 4; ++c) {
        size_t r0 = (size_t)c * 8192;
        gemm_mfma_cat_kernel<<<dim3(64, 8), 256, 0, stream>>>(x1 + r0 * 64, x2 + r0 * 64,
                                                              x3 + r0 * 64, WlT, bl, act1, 1024);
        gemm_mfma_kernel<1024, 1><<<dim3(64, 2), 256, 0, stream>>>(act1, Wm1T, bm1, act2, 256, 1);
        tail_kernel<<<128, 256, 0, stream>>>(act2, Wm2T, bm2, Wo, bo, out + r0 * C_);
    }
}

// Round 19
// 895.255 us; speedup vs baseline: 1.1074x; 1.1074x over previous
//
#include <hip/hip_runtime.h>
#include <cstddef>
#include <cstdint>

constexpr int B_ = 8, P_ = 4096, K_ = 20, H_ = 64, C_ = 40;
constexpr int NPT = B_ * P_;
#define NEG_SLOPE 0.2f

typedef unsigned long long u64;
typedef unsigned int u32;
typedef unsigned short u16;
typedef __attribute__((ext_vector_type(8))) short bf16x8;
typedef __attribute__((ext_vector_type(4))) float f32x4;

__device__ inline u16 f2bf(float v) {   // round-to-nearest-even bf16
    u32 bits = __float_as_uint(v);
    return (u16)((bits + 0x7FFFu + ((bits >> 16) & 1)) >> 16);
}
__device__ inline float bf2f(u16 h) { return __uint_as_float((u32)h << 16); }

// sorted-ascending 20-slot bubble insert, f32 keys (positive, bit-ordered)
__device__ __forceinline__ void bubble20f(float (&a)[K_], float key) {
    float carry = key;
#pragma unroll
    for (int s = 0; s < K_; ++s) {
        float as = a[s];
        a[s]  = fminf(carry, as);
        carry = fmaxf(carry, as);
    }
}
// key = (dist_bits & ~0xFFF) | cid   (cid < 4096; dist >= 0 finite)
__device__ __forceinline__ float mkkey(float dist, int cid) {
    return __uint_as_float((__float_as_uint(dist) & 0xFFFFF000u) | (u32)cid);
}

// ---------------------------------------------------------------- fused d2 + h/m split (D=64)
__global__ __launch_bounds__(256) void d2cvt2_kernel(const float* __restrict__ x,
                                                     float* __restrict__ d2,
                                                     u16* __restrict__ xh,
                                                     u16* __restrict__ xm) {
    int i = blockIdx.x * 256 + threadIdx.x;
    if (i >= NPT) return;
    const float* r = x + (size_t)i * 64;
    float s = 0.f;
#pragma unroll
    for (int d8 = 0; d8 < 64; d8 += 8) {
        float4 v0 = *(const float4*)(r + d8);
        float4 v1 = *(const float4*)(r + d8 + 4);
        s += v0.x * v0.x + v0.y * v0.y + v0.z * v0.z + v0.w * v0.w;
        s += v1.x * v1.x + v1.y * v1.y + v1.z * v1.z + v1.w * v1.w;
        float av[8] = {v0.x, v0.y, v0.z, v0.w, v1.x, v1.y, v1.z, v1.w};
        bf16x8 vh, vm;
#pragma unroll
        for (int j = 0; j < 8; ++j) {
            u16 h = f2bf(av[j]);
            float r1 = av[j] - bf2f(h);
            vh[j] = (short)h; vm[j] = (short)f2bf(r1);
        }
        *(bf16x8*)(xh + (size_t)i * 64 + d8) = vh;
        *(bf16x8*)(xm + (size_t)i * 64 + d8) = vm;
    }
    d2[i] = s;
}

// ---------------------------------------------------------------- layer-1 knn (D=3), direct register eval, inline d2
__global__ __launch_bounds__(256) void knnf3_kernel(const float* __restrict__ x,
                                                    int* __restrict__ idx) {
    __shared__ float sC[64][4];   // cand x,y,z,d2

    int b = blockIdx.y;
    int q0 = blockIdx.x * 64;
    const float* xc = x + (size_t)b * P_ * 3;

    int t = threadIdx.x, w = t >> 6, ln = t & 63;
    int q  = ln & 15;
    int ss = ln >> 4;

    int qrow = q0 + w * 16 + q;
    float qx = xc[(size_t)qrow * 3];
    float qy = xc[(size_t)qrow * 3 + 1];
    float qz = xc[(size_t)qrow * 3 + 2];
    float qd2 = qx * qx + qy * qy + qz * qz;

    float a[K_];
#pragma unroll
    for (int s = 0; s < K_; ++s)
        a[s] = __uint_as_float(0x7F7FF000u | (u32)s);    // distinct huge finite sentinels
    const float PINV = __uint_as_float(0x7F800000u);     // +inf
    const float BIGF = __uint_as_float(0x7F7FFFFFu);     // FLT_MAX

    float p0 = PINV, p1 = PINV, p2 = PINV, p3 = PINV;
    int pcnt = 0;
    float kthr = BIGF;

    int scc = t >> 2, scm = t & 3;   // staging: one value per thread

#pragma unroll 1
    for (int c0 = 0; c0 < P_; c0 += 64) {
        __syncthreads();   // prev chunk reads done
        if (scm < 3) {
            sC[scc][scm] = xc[(size_t)(c0 + scc) * 3 + scm];
        } else {
            float ax = xc[(size_t)(c0 + scc) * 3];
            float ay = xc[(size_t)(c0 + scc) * 3 + 1];
            float az = xc[(size_t)(c0 + scc) * 3 + 2];
            sC[scc][3] = ax * ax + ay * ay + az * az;
        }
        __syncthreads();   // tile ready

#pragma unroll
        for (int nt = 0; nt < 4; ++nt) {
#pragma unroll
            for (int r = 0; r < 4; ++r) {
                int cl = nt * 16 + ss * 4 + r;
                int cID = c0 + cl;
                float4 cv = *(const float4*)&sC[cl][0];
                float dv = (qd2 + cv.w) - 2.f * (qx * cv.x + qy * cv.y + qz * cv.z);
                if (cID == qrow) dv += 1e10f;
                dv = fmaxf(dv, 0.f);
                if (__any(dv <= kthr)) {
                    float key = mkkey(dv, cID);
                    bool pass = key < a[K_ - 1];
                    p3 = pass ? p2 : p3;
                    p2 = pass ? p1 : p2;
                    p1 = pass ? p0 : p1;
                    p0 = pass ? key : p0;
                    pcnt = pass ? pcnt + 1 : pcnt;
                    if (__any(pcnt >= 4)) {
                        bubble20f(a, p3); bubble20f(a, p2); bubble20f(a, p1); bubble20f(a, p0);
                        p0 = p1 = p2 = p3 = PINV; pcnt = 0;
                        kthr = __uint_as_float(__float_as_uint(a[K_ - 1]) | 0xFFFu);
                    }
                }
            }
        }
    }
    bubble20f(a, p3); bubble20f(a, p2); bubble20f(a, p1); bubble20f(a, p0);

    int* op = idx + ((size_t)(b * P_ + qrow)) * K_;
#pragma unroll 1
    for (int k = 0; k < K_; ++k) {
        float v = a[0];
        float v1 = __shfl_xor(v, 16);
        v = fminf(v, v1);
        float v2 = __shfl_xor(v, 32);
        v = fminf(v, v2);
        bool win = (__float_as_uint(a[0]) == __float_as_uint(v));
#pragma unroll
        for (int s = 0; s < K_ - 1; ++s) a[s] = win ? a[s + 1] : a[s];
        a[K_ - 1] = win ? BIGF : a[K_ - 1];
        if (ss == 0)
            op[k] = b * P_ + (int)(__float_as_uint(v) & 0xFFFu);
    }
}

// ---------------------------------------------------------------- fused knn (D=64) via MFMA, 3-product h/m
// R17-exact: full sd2[P_] stage (all 256 threads, once).
__global__ __launch_bounds__(256) void knnm64_kernel(const u16* __restrict__ xh,
                                                     const u16* __restrict__ xm,
                                                     const float* __restrict__ d2,
                                                     int* __restrict__ idx) {
    __shared__ u16 sH[64 * 64];      // elem (r,k) at byte r*128 + ((k*2) ^ ((r&7)<<4))
    __shared__ u16 sM[64 * 64];
    __shared__ float sd2[P_];        // 16 KB

    int b = blockIdx.y;
    int q0 = blockIdx.x * 64;
    const u16* xhb = xh + (size_t)b * P_ * 64;
    const u16* xmb = xm + (size_t)b * P_ * 64;
    const float* d2b = d2 + (size_t)b * P_;

    int t = threadIdx.x, w = t >> 6, ln = t & 63;
    int q  = ln & 15;
    int ss = ln >> 4;

    for (int i = t; i < P_ / 4; i += 256)
        ((float4*)sd2)[i] = ((const float4*)d2b)[i];

    int qrow = q0 + w * 16 + q;
    bf16x8 qh[2], qm[2];
#pragma unroll
    for (int kt = 0; kt < 2; ++kt) {
        size_t off = (size_t)qrow * 64 + kt * 32 + ss * 8;
        qh[kt] = *(const bf16x8*)(xhb + off);
        qm[kt] = *(const bf16x8*)(xmb + off);
    }

    __syncthreads();
    float qd2 = sd2[qrow];

    float a[K_];
#pragma unroll
    for (int s = 0; s < K_; ++s)
        a[s] = __uint_as_float(0x7F7FF000u | (u32)s);
    const float PINV = __uint_as_float(0x7F800000u);     // +inf
    const float BIGF = __uint_as_float(0x7F7FFFFFu);     // FLT_MAX

    float p0 = PINV, p1 = PINV, p2 = PINV, p3 = PINV;
    int pcnt = 0;
    float kthr = BIGF;

    int sr = t >> 2;
    int sk2 = (t & 3) * 32;
    int sbase = sr * 128, sswz = (sr & 7) << 4;
    size_t sgof = (size_t)sr * 64 + (t & 3) * 16;

#pragma unroll 1
    for (int c0 = 0; c0 < P_; c0 += 64) {
        __syncthreads();
        {
            size_t g = (size_t)c0 * 64 + sgof;
            bf16x8 h0 = *(const bf16x8*)(xhb + g);
            bf16x8 h1 = *(const bf16x8*)(xhb + g + 8);
            bf16x8 m0 = *(const bf16x8*)(xmb + g);
            bf16x8 m1 = *(const bf16x8*)(xmb + g + 8);
            *(bf16x8*)((char*)sH + sbase + (sk2 ^ sswz)) = h0;
            *(bf16x8*)((char*)sH + sbase + ((sk2 + 16) ^ sswz)) = h1;
            *(bf16x8*)((char*)sM + sbase + (sk2 ^ sswz)) = m0;
            *(bf16x8*)((char*)sM + sbase + ((sk2 + 16) ^ sswz)) = m1;
        }
        __syncthreads();

        f32x4 acc[4];
#pragma unroll
        for (int nt = 0; nt < 4; ++nt) {
            acc[nt] = (f32x4){0.f, 0.f, 0.f, 0.f};
            int r = nt * 16 + q;
            int base = r * 128, swz = (r & 7) << 4;
#pragma unroll
            for (int kt = 0; kt < 2; ++kt) {
                int k2 = kt * 64 + ss * 16;
                bf16x8 ch = *(const bf16x8*)((char*)sH + base + (k2 ^ swz));
                bf16x8 cm = *(const bf16x8*)((char*)sM + base + (k2 ^ swz));
                // 3-product split: hh + hm + mh
                acc[nt] = __builtin_amdgcn_mfma_f32_16x16x32_bf16(cm, qh[kt], acc[nt], 0, 0, 0);
                acc[nt] = __builtin_amdgcn_mfma_f32_16x16x32_bf16(ch, qm[kt], acc[nt], 0, 0, 0);
                acc[nt] = __builtin_amdgcn_mfma_f32_16x16x32_bf16(ch, qh[kt], acc[nt], 0, 0, 0);
            }
        }

        float dvv[4][4];
        float mn = 3.4e38f;
#pragma unroll
        for (int nt = 0; nt < 4; ++nt) {
#pragma unroll
            for (int r = 0; r < 4; ++r) {
                int cID = c0 + nt * 16 + ss * 4 + r;
                float dv = (qd2 + sd2[cID]) - 2.f * acc[nt][r];
                if (cID == qrow) dv += 1e10f;
                dv = fmaxf(dv, 0.f);
                dvv[nt][r] = dv;
                mn = fminf(mn, dv);
            }
        }
        if (__any(mn <= kthr)) {
#pragma unroll
            for (int nt = 0; nt < 4; ++nt) {
#pragma unroll
                for (int r = 0; r < 4; ++r) {
                    float dv = dvv[nt][r];
                    if (__any(dv <= kthr)) {
                        float key = mkkey(dv, c0 + nt * 16 + ss * 4 + r);
                        bool pass = key < a[K_ - 1];
                        p3 = pass ? p2 : p3;
                        p2 = pass ? p1 : p2;
                        p1 = pass ? p0 : p1;
                        p0 = pass ? key : p0;
                        pcnt = pass ? pcnt + 1 : pcnt;
                        if (__any(pcnt >= 4)) {
                            bubble20f(a, p3); bubble20f(a, p2); bubble20f(a, p1); bubble20f(a, p0);
                            p0 = p1 = p2 = p3 = PINV; pcnt = 0;
                            kthr = __uint_as_float(__float_as_uint(a[K_ - 1]) | 0xFFFu);
                        }
                    }
                }
            }
        }
    }
    bubble20f(a, p3); bubble20f(a, p2); bubble20f(a, p1); bubble20f(a, p0);

    int* op = idx + ((size_t)(b * P_ + qrow)) * K_;
#pragma unroll 1
    for (int k = 0; k < K_; ++k) {
        float v = a[0];
        float v1 = __shfl_xor(v, 16);
        v = fminf(v, v1);
        float v2 = __shfl_xor(v, 32);
        v = fminf(v, v2);
        bool win = (__float_as_uint(a[0]) == __float_as_uint(v));
#pragma unroll
        for (int s = 0; s < K_ - 1; ++s) a[s] = win ? a[s + 1] : a[s];
        a[K_ - 1] = win ? BIGF : a[K_ - 1];
        if (ss == 0)
            op[k] = b * P_ + (int)(__float_as_uint(v) & 0xFFFu);
    }
}

// ---------------------------------------------------------------- one-shot weight prep
__global__ __launch_bounds__(256) void prep_kernel(const float* __restrict__ W2,
                                                   const float* __restrict__ b2,
                                                   const float* __restrict__ W3,
                                                   const float* __restrict__ b3,
                                                   const float* __restrict__ Wl,
                                                   const float* __restrict__ Wm1,
                                                   const float* __restrict__ Wm2,
                                                   float* __restrict__ Wpk2, float* __restrict__ bpk2,
                                                   float* __restrict__ Wpk3, float* __restrict__ bpk3,
                                                   u16* __restrict__ WlT,
                                                   u16* __restrict__ Wm1T,
                                                   u16* __restrict__ Wm2T) {
    int t = blockIdx.x * 256 + threadIdx.x;
    if (t < 8192) {
        int d = t >> 7, h2 = t & 127;
        Wpk2[t] = (h2 < 64) ? W2[d * 64 + h2] : W2[(64 + d) * 64 + (h2 - 64)];
        if (t < 128) bpk2[t] = (t < 64) ? b2[t] : 0.f;
    } else if (t < 16384) {
        int t2 = t - 8192;
        int d = t2 >> 7, h2 = t2 & 127;
        Wpk3[t2] = (h2 < 64) ? W3[d * 64 + h2] : W3[(64 + d) * 64 + (h2 - 64)];
        if (t2 < 128) bpk3[t2] = (t2 < 64) ? b3[t2] : 0.f;
    } else if (t < 212992) {
        int t2 = t - 16384;
        int k = t2 >> 10, n = t2 & 1023;
        WlT[(size_t)n * 192 + k] = f2bf(Wl[t2]);
    } else if (t < 475136) {
        int t2 = t - 212992;
        int k = t2 >> 8, n = t2 & 255;
        Wm1T[(size_t)n * 1024 + k] = f2bf(Wm1[t2]);
    } else if (t < 507904) {
        int t2 = t - 475136;
        int k = t2 >> 7, n = t2 & 127;
        Wm2T[(size_t)n * 256 + k] = f2bf(Wm2[t2]);
    }
}

// ---------------------------------------------------------------- layer-1 UV (D=3, direct)
__global__ __launch_bounds__(256) void uv3_kernel(const float* __restrict__ x,
                                                  const float* __restrict__ W,
                                                  const float* __restrict__ b,
                                                  float* __restrict__ UV) {
    int t = blockIdx.x * 256 + threadIdx.x;
    int p = t >> 7, h2 = t & 127;
    float x0 = x[p * 3], x1 = x[p * 3 + 1], x2 = x[p * 3 + 2];
    float r;
    if (h2 < 64) {
        r = b[h2] + x0 * W[h2] + x1 * W[64 + h2] + x2 * W[128 + h2];
    } else {
        int h = h2 - 64;
        r = x0 * W[192 + h] + x1 * W[256 + h] + x2 * W[320 + h];
    }
    UV[t] = r;
}

// ---------------------------------------------------------------- edge max
__global__ __launch_bounds__(256) void edgemax_kernel(const float* __restrict__ UV,
                                                      const int* __restrict__ idx,
                                                      float* __restrict__ xout) {
    int wv = threadIdx.x >> 6, lane = threadIdx.x & 63;
    int p = blockIdx.x * 4 + wv;
    const float* uvp = UV + (size_t)p * 128;
    float duv = uvp[lane] - uvp[64 + lane];
    const int* ip = idx + (size_t)p * K_;
    int jj[K_];
#pragma unroll
    for (int k = 0; k < K_; ++k) jj[k] = ip[k];
    float m = -3.4e38f;
#pragma unroll
    for (int k = 0; k < K_; ++k) {
        float vj = UV[(size_t)jj[k] * 128 + 64 + lane];
        float t = duv + vj;
        m = fmaxf(m, fmaxf(t, NEG_SLOPE * t));
    }
    xout[(size_t)p * H_ + lane] = m;
}

// ---------------------------------------------------------------- GEMM 64x64 f32 (UV)
__global__ __launch_bounds__(256) void gemm_kernel(const float* __restrict__ A1,
                                                   const float* __restrict__ Wm,
                                                   const float* __restrict__ bias,
                                                   float* __restrict__ Cm,
                                                   int M, int N, int Kd, int leaky) {
    __shared__ float sA[32][68];
    __shared__ float sB[32][68];

    int tid = threadIdx.x;
    int row0 = blockIdx.x * 64, col0 = blockIdx.y * 64;
    int tx = tid & 15, ty = tid >> 4;

    int lr  = tid >> 2;
    int lk4 = (tid & 3) * 4;
    int lkb = tid >> 4;
    int lnb = (tid & 15) * 4;

    float acc[4][4] = {};

    for (int k0 = 0; k0 < Kd; k0 += 32) {
        int arow = row0 + lr;
#pragma unroll
        for (int h = 0; h < 32; h += 16) {
            int kk = k0 + lk4 + h;
            const float* src = A1 + (size_t)arow * Kd + kk;
            float4 av = *(const float4*)src;
            sA[lk4 + h + 0][lr] = av.x; sA[lk4 + h + 1][lr] = av.y;
            sA[lk4 + h + 2][lr] = av.z; sA[lk4 + h + 3][lr] = av.w;
        }
        int bcol = col0 + lnb;
#pragma unroll
        for (int h = 0; h < 32; h += 16) {
            float4 bv = make_float4(0.f, 0.f, 0.f, 0.f);
            if (bcol < N) bv = *(const float4*)(Wm + (size_t)(k0 + lkb + h) * N + bcol);
            *(float4*)&sB[lkb + h][lnb] = bv;
        }
        __syncthreads();

#pragma unroll
        for (int kk2 = 0; kk2 < 32; ++kk2) {
            float4 a = *(const float4*)&sA[kk2][ty * 4];
            float4 bb = *(const float4*)&sB[kk2][tx * 4];
            acc[0][0] = fmaf(a.x, bb.x, acc[0][0]); acc[0][1] = fmaf(a.x, bb.y, acc[0][1]);
            acc[0][2] = fmaf(a.x, bb.z, acc[0][2]); acc[0][3] = fmaf(a.x, bb.w, acc[0][3]);
            acc[1][0] = fmaf(a.y, bb.x, acc[1][0]); acc[1][1] = fmaf(a.y, bb.y, acc[1][1]);
            acc[1][2] = fmaf(a.y, bb.z, acc[1][2]); acc[1][3] = fmaf(a.y, bb.w, acc[1][3]);
            acc[2][0] = fmaf(a.z, bb.x, acc[2][0]); acc[2][1] = fmaf(a.z, bb.y, acc[2][1]);
            acc[2][2] = fmaf(a.z, bb.z, acc[2][2]); acc[2][3] = fmaf(a.z, bb.w, acc[2][3]);
            acc[3][0] = fmaf(a.w, bb.x, acc[3][0]); acc[3][1] = fmaf(a.w, bb.y, acc[3][1]);
            acc[3][2] = fmaf(a.w, bb.z, acc[3][2]); acc[3][3] = fmaf(a.w, bb.w, acc[3][3]);
        }
        __syncthreads();
    }

    for (int i = 0; i < 4; ++i) {
        int row = row0 + ty * 4 + i;
        for (int j = 0; j < 4; ++j) {
            int col = col0 + tx * 4 + j;
            if (col < N) {
                float v = acc[i][j] + bias[col];
                if (leaky) v = v > 0.f ? v : NEG_SLOPE * v;
                Cm[(size_t)row * N + col] = v;
            }
        }
    }
}

// ---------------------------------------------------------------- MFMA GEMM head (bf16 A)
template <int KD, int OUT_BF16>
__global__ __launch_bounds__(256) void gemm_mfma_kernel(const u16* __restrict__ A,
                                                        const u16* __restrict__ BT,
                                                        const float* __restrict__ bias,
                                                        void* __restrict__ Cout,
                                                        int N, int leaky) {
    __shared__ u16 sA[128 * 64];
    __shared__ u16 sB[128 * 64];

    int t = threadIdx.x;
    int wave = t >> 6, lane = t & 63;
    int wm = wave >> 1, wn = wave & 1;
    int row0 = blockIdx.x * 128;
    int col0 = blockIdx.y * 128;

    f32x4 acc[4][4] = {};

    for (int k0 = 0; k0 < KD; k0 += 64) {
        __syncthreads();
#pragma unroll
        for (int i = 0; i < 4; ++i) {
            int li = t + i * 256;
            int r = li >> 3;
            int kc = (li & 7) * 8;
            bf16x8 v = *(const bf16x8*)(A + (size_t)(row0 + r) * KD + k0 + kc);
            *(bf16x8*)((char*)sA + r * 128 + ((kc * 2) ^ ((r & 7) << 4))) = v;
        }
#pragma unroll
        for (int i = 0; i < 4; ++i) {
            int li = t + i * 256;
            int n = li >> 3;
            int kc = (li & 7) * 8;
            bf16x8 v = *(const bf16x8*)(BT + (size_t)(col0 + n) * KD + k0 + kc);
            *(bf16x8*)((char*)sB + n * 128 + ((kc * 2) ^ ((n & 7) << 4))) = v;
        }
        __syncthreads();

#pragma unroll
        for (int kk = 0; kk < 2; ++kk) {
            int kb = kk * 64 + (lane >> 4) * 16;
            bf16x8 af[4], bfr[4];
#pragma unroll
            for (int mi = 0; mi < 4; ++mi) {
                int r = wm * 64 + mi * 16 + (lane & 15);
                af[mi] = *(const bf16x8*)((char*)sA + r * 128 + (kb ^ ((r & 7) << 4)));
            }
#pragma unroll
            for (int ni = 0; ni < 4; ++ni) {
                int n = wn * 64 + ni * 16 + (lane & 15);
                bfr[ni] = *(const bf16x8*)((char*)sB + n * 128 + (kb ^ ((n & 7) << 4)));
            }
#pragma unroll
            for (int mi = 0; mi < 4; ++mi)
#pragma unroll
                for (int ni = 0; ni < 4; ++ni)
                    acc[mi][ni] = __builtin_amdgcn_mfma_f32_16x16x32_bf16(
                        af[mi], bfr[ni], acc[mi][ni], 0, 0, 0);
        }
    }

#pragma unroll
    for (int ni = 0; ni < 4; ++ni) {
        int col = col0 + wn * 64 + ni * 16 + (lane & 15);
        float bs = bias[col];
#pragma unroll
        for (int mi = 0; mi < 4; ++mi) {
#pragma unroll
            for (int r = 0; r < 4; ++r) {
                int row = row0 + wm * 64 + mi * 16 + (lane >> 4) * 4 + r;
                float v = acc[mi][ni][r] + bs;
                if (leaky) v = v > 0.f ? v : NEG_SLOPE * v;
                if (OUT_BF16)
                    ((u16*)Cout)[(size_t)row * N + col] = f2bf(v);
                else
                    ((float*)Cout)[(size_t)row * N + col] = v;
            }
        }
    }
}

// ---------------------------------------------------------------- MFMA GEMM, cat-f32 A (fused cvt)
__global__ __launch_bounds__(256) void gemm_mfma_cat_kernel(const float* __restrict__ x1,
                                                            const float* __restrict__ x2,
                                                            const float* __restrict__ x3,
                                                            const u16* __restrict__ BT,
                                                            const float* __restrict__ bias,
                                                            u16* __restrict__ Cout,
                                                            int N) {
    __shared__ u16 sA[128 * 64];
    __shared__ u16 sB[128 * 64];

    int t = threadIdx.x;
    int wave = t >> 6, lane = t & 63;
    int wm = wave >> 1, wn = wave & 1;
    int row0 = blockIdx.x * 128;
    int col0 = blockIdx.y * 128;

    f32x4 acc[4][4] = {};

#pragma unroll 1
    for (int k0 = 0; k0 < 192; k0 += 64) {
        const float* src = (k0 == 0) ? x1 : (k0 == 64) ? x2 : x3;
        __syncthreads();
#pragma unroll
        for (int i = 0; i < 4; ++i) {
            int li = t + i * 256;
            int r = li >> 3;
            int kc = (li & 7) * 8;
            const float* sp = src + (size_t)(row0 + r) * 64 + kc;
            float4 a0 = *(const float4*)sp;
            float4 a1 = *(const float4*)(sp + 4);
            bf16x8 v;
            v[0] = (short)f2bf(a0.x); v[1] = (short)f2bf(a0.y);
            v[2] = (short)f2bf(a0.z); v[3] = (short)f2bf(a0.w);
            v[4] = (short)f2bf(a1.x); v[5] = (short)f2bf(a1.y);
            v[6] = (short)f2bf(a1.z); v[7] = (short)f2bf(a1.w);
            *(bf16x8*)((char*)sA + r * 128 + ((kc * 2) ^ ((r & 7) << 4))) = v;
        }
#pragma unroll
        for (int i = 0; i < 4; ++i) {
            int li = t + i * 256;
            int n = li >> 3;
            int kc = (li & 7) * 8;
            bf16x8 v = *(const bf16x8*)(BT + (size_t)(col0 + n) * 192 + k0 + kc);
            *(bf16x8*)((char*)sB + n * 128 + ((kc * 2) ^ ((n & 7) << 4))) = v;
        }
        __syncthreads();

#pragma unroll
        for (int kk = 0; kk < 2; ++kk) {
            int kb = kk * 64 + (lane >> 4) * 16;
            bf16x8 af[4], bfr[4];
#pragma unroll
            for (int mi = 0; mi < 4; ++mi) {
                int r = wm * 64 + mi * 16 + (lane & 15);
                af[mi] = *(const bf16x8*)((char*)sA + r * 128 + (kb ^ ((r & 7) << 4)));
            }
#pragma unroll
            for (int ni = 0; ni < 4; ++ni) {
                int n = wn * 64 + ni * 16 + (lane & 15);
                bfr[ni] = *(const bf16x8*)((char*)sB + n * 128 + (kb ^ ((n & 7) << 4)));
            }
#pragma unroll
            for (int mi = 0; mi < 4; ++mi)
#pragma unroll
                for (int ni = 0; ni < 4; ++ni)
                    acc[mi][ni] = __builtin_amdgcn_mfma_f32_16x16x32_bf16(
                        af[mi], bfr[ni], acc[mi][ni], 0, 0, 0);
        }
    }

#pragma unroll
    for (int ni = 0; ni < 4; ++ni) {
        int col = col0 + wn * 64 + ni * 16 + (lane & 15);
        float bs = bias[col];
#pragma unroll
        for (int mi = 0; mi < 4; ++mi) {
#pragma unroll
            for (int r = 0; r < 4; ++r) {
                int row = row0 + wm * 64 + mi * 16 + (lane >> 4) * 4 + r;
                float v = acc[mi][ni][r] + bs;
                v = v > 0.f ? v : NEG_SLOPE * v;
                Cout[(size_t)row * N + col] = f2bf(v);
            }
        }
    }
}

// ---------------------------------------------------------------- fused Wo GEMM + log_softmax
__global__ __launch_bounds__(256) void lsm_wo_kernel(const float* __restrict__ act3,
                                                     const float* __restrict__ Wo,
                                                     const float* __restrict__ bo,
                                                     float* __restrict__ out) {
    __shared__ float sWo[128 * 44];
    __shared__ float sAct[4][128];

    int t = threadIdx.x;
    for (int i = t; i < 128 * 40; i += 256) {
        int k = i / 40, c = i % 40;
        sWo[k * 44 + c] = Wo[i];
    }
    __syncthreads();

    int wv = t >> 6, lane = t & 63;
    int row = blockIdx.x * 4 + wv;
    sAct[wv][lane]      = act3[(size_t)row * 128 + lane];
    sAct[wv][64 + lane] = act3[(size_t)row * 128 + 64 + lane];

    float acc = (lane < C_) ? bo[lane] : -3.4e38f;
    if (lane < C_) {
#pragma unroll 8
        for (int k = 0; k < 128; ++k)
            acc = fmaf(sAct[wv][k], sWo[k * 44 + lane], acc);
    }
    float m = acc;
#pragma unroll
    for (int s = 1; s < 64; s <<= 1) m = fmaxf(m, __shfl_xor(m, s));
    float e = (lane < C_) ? expf(acc - m) : 0.f;
    float sum = e;
#pragma unroll
    for (int s = 1; s < 64; s <<= 1) sum += __shfl_xor(sum, s);
    if (lane < C_) out[(size_t)row * C_ + lane] = acc - m - logf(sum);
}

// ----------------------------------------------------------------
extern "C" void kernel_launch(void* const* d_in, const int* in_sizes, int n_in,
                              void* d_out, int out_size, void* d_ws, size_t ws_size,
                              hipStream_t stream) {
    const float* x   = (const float*)d_in[0];
    const float* W1  = (const float*)d_in[2];
    const float* b1  = (const float*)d_in[3];
    const float* W2  = (const float*)d_in[4];
    const float* b2  = (const float*)d_in[5];
    const float* W3  = (const float*)d_in[6];
    const float* b3  = (const float*)d_in[7];
    const float* Wl  = (const float*)d_in[8];
    const float* bl  = (const float*)d_in[9];
    const float* Wm1 = (const float*)d_in[10];
    const float* bm1 = (const float*)d_in[11];
    const float* Wm2 = (const float*)d_in[12];
    const float* bm2 = (const float*)d_in[13];
    const float* Wo  = (const float*)d_in[14];
    const float* bo  = (const float*)d_in[15];
    float* out = (float*)d_out;

    // ---- workspace (max 50,987,008 B — proven footprint) ----
    char* ws = (char*)d_ws;
    float* x1   = (float*)(ws);
    float* x2   = (float*)(ws + 8388608);
    float* x3   = (float*)(ws + 16777216);
    int*   idx  = (int*)  (ws + 25165824);
    float* d2   = (float*)(ws + 27787264);
    char* hb = ws + 27918336;
    u16*   xhs  = (u16*)(hb);                         // 4 MB
    u16*   xms  = (u16*)(hb + 4194304);               // 4 MB
    float* UV   = (float*)(hb);                       // 16 MB
    float* Wpk2 = (float*)(ws + 44695552);
    float* bpk2 = (float*)(ws + 44728320);
    float* Wpk3 = (float*)(ws + 44728832);
    float* bpk3 = (float*)(ws + 44761600);
    u16*   WlT  = (u16*)  (ws + 44762112);
    u16*   Wm1T = (u16*)  (ws + 45155328);
    u16*   Wm2T = (u16*)  (ws + 45679616);
    u16*   act1 = (u16*)(hb);
    u16*   act2 = (u16*)(ws + 45745152);
    float* act3 = (float*)(hb);

    prep_kernel<<<1984, 256, 0, stream>>>(W2, b2, W3, b3, Wl, Wm1, Wm2,
                                          Wpk2, bpk2, Wpk3, bpk3, WlT, Wm1T, Wm2T);

    // ---- layer 1 (D=3)
    knnf3_kernel<<<dim3(P_ / 64, B_), 256, 0, stream>>>(x, idx);
    uv3_kernel<<<NPT * 128 / 256, 256, 0, stream>>>(x, W1, b1, UV);
    edgemax_kernel<<<NPT / 4, 256, 0, stream>>>(UV, idx, x1);
    // ---- layer 2 (D=64)
    d2cvt2_kernel<<<NPT / 256, 256, 0, stream>>>(x1, d2, xhs, xms);
    knnm64_kernel<<<dim3(P_ / 64, B_), 256, 0, stream>>>(xhs, xms, d2, idx);
    gemm_kernel<<<dim3(NPT / 64, 2), 256, 0, stream>>>(x1, Wpk2, bpk2, UV, NPT, 128, 64, 0);
    edgemax_kernel<<<NPT / 4, 256, 0, stream>>>(UV, idx, x2);
    // ---- layer 3 (D=64)
    d2cvt2_kernel<<<NPT / 256, 256, 0, stream>>>(x2, d2, xhs, xms);
    knnm64_kernel<<<dim3(P_ / 64, B_), 256, 0, stream>>>(xhs, xms, d2, idx);
    gemm_kernel<<<dim3(NPT / 64, 2), 256, 0, stream>>>(x2, Wpk3, bpk3, UV, NPT, 128, 64, 0);
    edgemax_kernel<<<NPT / 4, 256, 0, stream>>>(UV, idx, x3);

    // ---- MLP head: 4 chunks of 8192 rows
    for (int c = 0; c < 4; ++c) {
        size_t r0 = (size_t)c * 8192;
        gemm_mfma_cat_kernel<<<dim3(64, 8), 256, 0, stream>>>(x1 + r0 * 64, x2 + r0 * 64,
                                                              x3 + r0 * 64, WlT, bl, act1, 1024);
        gemm_mfma_kernel<1024, 1><<<dim3(64, 2), 256, 0, stream>>>(act1, Wm1T, bm1, act2, 256, 1);
        gemm_mfma_kernel<256, 0><<<dim3(64, 1), 256, 0, stream>>>(act2, Wm2T, bm2, act3, 128, 1);
        lsm_wo_kernel<<<2048, 256, 0, stream>>>(act3, Wo, bo, out + r0 * C_);
    }
}

// Round 20
// 889.081 us; speedup vs baseline: 1.1151x; 1.0069x over previous
//
#include <hip/hip_runtime.h>
#include <cstddef>
#include <cstdint>

constexpr int B_ = 8, P_ = 4096, K_ = 20, H_ = 64, C_ = 40;
constexpr int NPT = B_ * P_;
#define NEG_SLOPE 0.2f

typedef unsigned long long u64;
typedef unsigned int u32;
typedef unsigned short u16;
typedef __attribute__((ext_vector_type(8))) short bf16x8;
typedef __attribute__((ext_vector_type(4))) float f32x4;

__device__ inline u16 f2bf(float v) {   // round-to-nearest-even bf16
    u32 bits = __float_as_uint(v);
    return (u16)((bits + 0x7FFFu + ((bits >> 16) & 1)) >> 16);
}
__device__ inline float bf2f(u16 h) { return __uint_as_float((u32)h << 16); }

// sorted-ascending 20-slot bubble insert, f32 keys (positive, bit-ordered)
__device__ __forceinline__ void bubble20f(float (&a)[K_], float key) {
    float carry = key;
#pragma unroll
    for (int s = 0; s < K_; ++s) {
        float as = a[s];
        a[s]  = fminf(carry, as);
        carry = fmaxf(carry, as);
    }
}
// key = (dist_bits & ~0xFFF) | cid   (cid < 4096; dist >= 0 finite)
__device__ __forceinline__ float mkkey(float dist, int cid) {
    return __uint_as_float((__float_as_uint(dist) & 0xFFFFF000u) | (u32)cid);
}

// ---------------------------------------------------------------- pack x -> (x,y,z,d2) float4
__global__ __launch_bounds__(256) void pack4_kernel(const float* __restrict__ x,
                                                    float4* __restrict__ xp) {
    int i = blockIdx.x * 256 + threadIdx.x;
    if (i >= NPT) return;
    float ax = x[(size_t)i * 3], ay = x[(size_t)i * 3 + 1], az = x[(size_t)i * 3 + 2];
    xp[i] = make_float4(ax, ay, az, ax * ax + ay * ay + az * az);
}

// ---------------------------------------------------------------- fused d2 + h/m split (D=64)
__global__ __launch_bounds__(256) void d2cvt2_kernel(const float* __restrict__ x,
                                                     float* __restrict__ d2,
                                                     u16* __restrict__ xh,
                                                     u16* __restrict__ xm) {
    int i = blockIdx.x * 256 + threadIdx.x;
    if (i >= NPT) return;
    const float* r = x + (size_t)i * 64;
    float s = 0.f;
#pragma unroll
    for (int d8 = 0; d8 < 64; d8 += 8) {
        float4 v0 = *(const float4*)(r + d8);
        float4 v1 = *(const float4*)(r + d8 + 4);
        s += v0.x * v0.x + v0.y * v0.y + v0.z * v0.z + v0.w * v0.w;
        s += v1.x * v1.x + v1.y * v1.y + v1.z * v1.z + v1.w * v1.w;
        float av[8] = {v0.x, v0.y, v0.z, v0.w, v1.x, v1.y, v1.z, v1.w};
        bf16x8 vh, vm;
#pragma unroll
        for (int j = 0; j < 8; ++j) {
            u16 h = f2bf(av[j]);
            float r1 = av[j] - bf2f(h);
            vh[j] = (short)h; vm[j] = (short)f2bf(r1);
        }
        *(bf16x8*)(xh + (size_t)i * 64 + d8) = vh;
        *(bf16x8*)(xm + (size_t)i * 64 + d8) = vm;
    }
    d2[i] = s;
}

// ---------------------------------------------------------------- layer-1 knn (D=3): barrier-free,
// LDS-free; candidates loaded directly from L2-resident packed xp (16-lane broadcast).
__global__ __launch_bounds__(256) void knnf3_kernel(const float4* __restrict__ xp,
                                                    int* __restrict__ idx) {
    int b = blockIdx.y;
    int q0 = blockIdx.x * 64;
    const float4* xb = xp + (size_t)b * P_;

    int t = threadIdx.x, w = t >> 6, ln = t & 63;
    int q  = ln & 15;
    int ss = ln >> 4;

    int qrow = q0 + w * 16 + q;
    float4 qv = xb[qrow];

    float a[K_];
#pragma unroll
    for (int s = 0; s < K_; ++s)
        a[s] = __uint_as_float(0x7F7FF000u | (u32)s);    // distinct huge finite sentinels
    const float PINV = __uint_as_float(0x7F800000u);     // +inf
    const float BIGF = __uint_as_float(0x7F7FFFFFu);     // FLT_MAX

    float p0 = PINV, p1 = PINV, p2 = PINV, p3 = PINV;
    int pcnt = 0;
    float kthr = BIGF;

#pragma unroll 1
    for (int c0 = 0; c0 < P_; c0 += 64) {
#pragma unroll
        for (int nt = 0; nt < 4; ++nt) {
            // load this group's 4 candidates (16-lane broadcast via L2)
            float4 cv[4];
#pragma unroll
            for (int r = 0; r < 4; ++r)
                cv[r] = xb[c0 + nt * 16 + ss * 4 + r];
#pragma unroll
            for (int r = 0; r < 4; ++r) {
                int cID = c0 + nt * 16 + ss * 4 + r;
                float dv = (qv.w + cv[r].w)
                         - 2.f * (qv.x * cv[r].x + qv.y * cv[r].y + qv.z * cv[r].z);
                if (cID == qrow) dv += 1e10f;
                dv = fmaxf(dv, 0.f);
                if (__any(dv <= kthr)) {
                    float key = mkkey(dv, cID);
                    bool pass = key < a[K_ - 1];
                    p3 = pass ? p2 : p3;
                    p2 = pass ? p1 : p2;
                    p1 = pass ? p0 : p1;
                    p0 = pass ? key : p0;
                    pcnt = pass ? pcnt + 1 : pcnt;
                    if (__any(pcnt >= 4)) {
                        bubble20f(a, p3); bubble20f(a, p2); bubble20f(a, p1); bubble20f(a, p0);
                        p0 = p1 = p2 = p3 = PINV; pcnt = 0;
                        kthr = __uint_as_float(__float_as_uint(a[K_ - 1]) | 0xFFFu);
                    }
                }
            }
        }
    }
    bubble20f(a, p3); bubble20f(a, p2); bubble20f(a, p1); bubble20f(a, p0);

    int* op = idx + ((size_t)(b * P_ + qrow)) * K_;
#pragma unroll 1
    for (int k = 0; k < K_; ++k) {
        float v = a[0];
        float v1 = __shfl_xor(v, 16);
        v = fminf(v, v1);
        float v2 = __shfl_xor(v, 32);
        v = fminf(v, v2);
        bool win = (__float_as_uint(a[0]) == __float_as_uint(v));
#pragma unroll
        for (int s = 0; s < K_ - 1; ++s) a[s] = win ? a[s + 1] : a[s];
        a[K_ - 1] = win ? BIGF : a[K_ - 1];
        if (ss == 0)
            op[k] = b * P_ + (int)(__float_as_uint(v) & 0xFFFu);
    }
}

// ---------------------------------------------------------------- fused knn (D=64) via MFMA, 3-product h/m
// Candidate chunk = 128 (half the barriers of chunk-64).
__global__ __launch_bounds__(256) void knnm64_kernel(const u16* __restrict__ xh,
                                                     const u16* __restrict__ xm,
                                                     const float* __restrict__ d2,
                                                     int* __restrict__ idx) {
    __shared__ u16 sH[128 * 64];     // elem (r,k) at byte r*128 + ((k*2) ^ ((r&7)<<4)); 16 KB
    __shared__ u16 sM[128 * 64];     // 16 KB
    __shared__ float sd2[P_];        // 16 KB

    int b = blockIdx.y;
    int q0 = blockIdx.x * 64;
    const u16* xhb = xh + (size_t)b * P_ * 64;
    const u16* xmb = xm + (size_t)b * P_ * 64;
    const float* d2b = d2 + (size_t)b * P_;

    int t = threadIdx.x, w = t >> 6, ln = t & 63;
    int q  = ln & 15;
    int ss = ln >> 4;

    for (int i = t; i < P_ / 4; i += 256)
        ((float4*)sd2)[i] = ((const float4*)d2b)[i];

    int qrow = q0 + w * 16 + q;
    bf16x8 qh[2], qm[2];
#pragma unroll
    for (int kt = 0; kt < 2; ++kt) {
        size_t off = (size_t)qrow * 64 + kt * 32 + ss * 8;
        qh[kt] = *(const bf16x8*)(xhb + off);
        qm[kt] = *(const bf16x8*)(xmb + off);
    }

    __syncthreads();
    float qd2 = sd2[qrow];

    float a[K_];
#pragma unroll
    for (int s = 0; s < K_; ++s)
        a[s] = __uint_as_float(0x7F7FF000u | (u32)s);
    const float PINV = __uint_as_float(0x7F800000u);     // +inf
    const float BIGF = __uint_as_float(0x7F7FFFFFu);     // FLT_MAX

    float p0 = PINV, p1 = PINV, p2 = PINV, p3 = PINV;
    int pcnt = 0;
    float kthr = BIGF;

    // staging: 2 threads per row, 32 elems (4x bf16x8) each per array
    int sr = t >> 1;                 // row 0..127
    int half = t & 1;
    int sbase = sr * 128, sswz = (sr & 7) << 4;
    size_t sgof = (size_t)sr * 64 + half * 32;
    int kb0 = half * 64;             // byte base within row

#pragma unroll 1
    for (int c0 = 0; c0 < P_; c0 += 128) {
        __syncthreads();
        {
            size_t g = (size_t)c0 * 64 + sgof;
#pragma unroll
            for (int e = 0; e < 4; ++e) {
                bf16x8 hv = *(const bf16x8*)(xhb + g + e * 8);
                bf16x8 mv = *(const bf16x8*)(xmb + g + e * 8);
                int k2 = kb0 + e * 16;
                *(bf16x8*)((char*)sH + sbase + (k2 ^ sswz)) = hv;
                *(bf16x8*)((char*)sM + sbase + (k2 ^ sswz)) = mv;
            }
        }
        __syncthreads();

        f32x4 acc[8];
#pragma unroll
        for (int nt = 0; nt < 8; ++nt) {
            acc[nt] = (f32x4){0.f, 0.f, 0.f, 0.f};
            int r = nt * 16 + q;
            int base = r * 128, swz = (r & 7) << 4;
#pragma unroll
            for (int kt = 0; kt < 2; ++kt) {
                int k2 = kt * 64 + ss * 16;
                bf16x8 ch = *(const bf16x8*)((char*)sH + base + (k2 ^ swz));
                bf16x8 cm = *(const bf16x8*)((char*)sM + base + (k2 ^ swz));
                // 3-product split: hh + hm + mh
                acc[nt] = __builtin_amdgcn_mfma_f32_16x16x32_bf16(cm, qh[kt], acc[nt], 0, 0, 0);
                acc[nt] = __builtin_amdgcn_mfma_f32_16x16x32_bf16(ch, qm[kt], acc[nt], 0, 0, 0);
                acc[nt] = __builtin_amdgcn_mfma_f32_16x16x32_bf16(ch, qh[kt], acc[nt], 0, 0, 0);
            }
        }

        float dvv[8][4];
        float mn = 3.4e38f;
#pragma unroll
        for (int nt = 0; nt < 8; ++nt) {
#pragma unroll
            for (int r = 0; r < 4; ++r) {
                int cID = c0 + nt * 16 + ss * 4 + r;
                float dv = (qd2 + sd2[cID]) - 2.f * acc[nt][r];
                if (cID == qrow) dv += 1e10f;
                dv = fmaxf(dv, 0.f);
                dvv[nt][r] = dv;
                mn = fminf(mn, dv);
            }
        }
        if (__any(mn <= kthr)) {
#pragma unroll
            for (int nt = 0; nt < 8; ++nt) {
#pragma unroll
                for (int r = 0; r < 4; ++r) {
                    float dv = dvv[nt][r];
                    if (__any(dv <= kthr)) {
                        float key = mkkey(dv, c0 + nt * 16 + ss * 4 + r);
                        bool pass = key < a[K_ - 1];
                        p3 = pass ? p2 : p3;
                        p2 = pass ? p1 : p2;
                        p1 = pass ? p0 : p1;
                        p0 = pass ? key : p0;
                        pcnt = pass ? pcnt + 1 : pcnt;
                        if (__any(pcnt >= 4)) {
                            bubble20f(a, p3); bubble20f(a, p2); bubble20f(a, p1); bubble20f(a, p0);
                            p0 = p1 = p2 = p3 = PINV; pcnt = 0;
                            kthr = __uint_as_float(__float_as_uint(a[K_ - 1]) | 0xFFFu);
                        }
                    }
                }
            }
        }
    }
    bubble20f(a, p3); bubble20f(a, p2); bubble20f(a, p1); bubble20f(a, p0);

    int* op = idx + ((size_t)(b * P_ + qrow)) * K_;
#pragma unroll 1
    for (int k = 0; k < K_; ++k) {
        float v = a[0];
        float v1 = __shfl_xor(v, 16);
        v = fminf(v, v1);
        float v2 = __shfl_xor(v, 32);
        v = fminf(v, v2);
        bool win = (__float_as_uint(a[0]) == __float_as_uint(v));
#pragma unroll
        for (int s = 0; s < K_ - 1; ++s) a[s] = win ? a[s + 1] : a[s];
        a[K_ - 1] = win ? BIGF : a[K_ - 1];
        if (ss == 0)
            op[k] = b * P_ + (int)(__float_as_uint(v) & 0xFFFu);
    }
}

// ---------------------------------------------------------------- one-shot weight prep
__global__ __launch_bounds__(256) void prep_kernel(const float* __restrict__ W2,
                                                   const float* __restrict__ b2,
                                                   const float* __restrict__ W3,
                                                   const float* __restrict__ b3,
                                                   const float* __restrict__ Wl,
                                                   const float* __restrict__ Wm1,
                                                   const float* __restrict__ Wm2,
                                                   float* __restrict__ Wpk2, float* __restrict__ bpk2,
                                                   float* __restrict__ Wpk3, float* __restrict__ bpk3,
                                                   u16* __restrict__ WlT,
                                                   u16* __restrict__ Wm1T,
                                                   u16* __restrict__ Wm2T) {
    int t = blockIdx.x * 256 + threadIdx.x;
    if (t < 8192) {
        int d = t >> 7, h2 = t & 127;
        Wpk2[t] = (h2 < 64) ? W2[d * 64 + h2] : W2[(64 + d) * 64 + (h2 - 64)];
        if (t < 128) bpk2[t] = (t < 64) ? b2[t] : 0.f;
    } else if (t < 16384) {
        int t2 = t - 8192;
        int d = t2 >> 7, h2 = t2 & 127;
        Wpk3[t2] = (h2 < 64) ? W3[d * 64 + h2] : W3[(64 + d) * 64 + (h2 - 64)];
        if (t2 < 128) bpk3[t2] = (t2 < 64) ? b3[t2] : 0.f;
    } else if (t < 212992) {
        int t2 = t - 16384;
        int k = t2 >> 10, n = t2 & 1023;
        WlT[(size_t)n * 192 + k] = f2bf(Wl[t2]);
    } else if (t < 475136) {
        int t2 = t - 212992;
        int k = t2 >> 8, n = t2 & 255;
        Wm1T[(size_t)n * 1024 + k] = f2bf(Wm1[t2]);
    } else if (t < 507904) {
        int t2 = t - 475136;
        int k = t2 >> 7, n = t2 & 127;
        Wm2T[(size_t)n * 256 + k] = f2bf(Wm2[t2]);
    }
}

// ---------------------------------------------------------------- layer-1 UV (D=3, direct)
__global__ __launch_bounds__(256) void uv3_kernel(const float* __restrict__ x,
                                                  const float* __restrict__ W,
                                                  const float* __restrict__ b,
                                                  float* __restrict__ UV) {
    int t = blockIdx.x * 256 + threadIdx.x;
    int p = t >> 7, h2 = t & 127;
    float x0 = x[p * 3], x1 = x[p * 3 + 1], x2 = x[p * 3 + 2];
    float r;
    if (h2 < 64) {
        r = b[h2] + x0 * W[h2] + x1 * W[64 + h2] + x2 * W[128 + h2];
    } else {
        int h = h2 - 64;
        r = x0 * W[192 + h] + x1 * W[256 + h] + x2 * W[320 + h];
    }
    UV[t] = r;
}

// ---------------------------------------------------------------- edge max
__global__ __launch_bounds__(256) void edgemax_kernel(const float* __restrict__ UV,
                                                      const int* __restrict__ idx,
                                                      float* __restrict__ xout) {
    int wv = threadIdx.x >> 6, lane = threadIdx.x & 63;
    int p = blockIdx.x * 4 + wv;
    const float* uvp = UV + (size_t)p * 128;
    float duv = uvp[lane] - uvp[64 + lane];
    const int* ip = idx + (size_t)p * K_;
    int jj[K_];
#pragma unroll
    for (int k = 0; k < K_; ++k) jj[k] = ip[k];
    float m = -3.4e38f;
#pragma unroll
    for (int k = 0; k < K_; ++k) {
        float vj = UV[(size_t)jj[k] * 128 + 64 + lane];
        float t = duv + vj;
        m = fmaxf(m, fmaxf(t, NEG_SLOPE * t));
    }
    xout[(size_t)p * H_ + lane] = m;
}

// ---------------------------------------------------------------- GEMM 64x64 f32 (UV)
__global__ __launch_bounds__(256) void gemm_kernel(const float* __restrict__ A1,
                                                   const float* __restrict__ Wm,
                                                   const float* __restrict__ bias,
                                                   float* __restrict__ Cm,
                                                   int M, int N, int Kd, int leaky) {
    __shared__ float sA[32][68];
    __shared__ float sB[32][68];

    int tid = threadIdx.x;
    int row0 = blockIdx.x * 64, col0 = blockIdx.y * 64;
    int tx = tid & 15, ty = tid >> 4;

    int lr  = tid >> 2;
    int lk4 = (tid & 3) * 4;
    int lkb = tid >> 4;
    int lnb = (tid & 15) * 4;

    float acc[4][4] = {};

    for (int k0 = 0; k0 < Kd; k0 += 32) {
        int arow = row0 + lr;
#pragma unroll
        for (int h = 0; h < 32; h += 16) {
            int kk = k0 + lk4 + h;
            const float* src = A1 + (size_t)arow * Kd + kk;
            float4 av = *(const float4*)src;
            sA[lk4 + h + 0][lr] = av.x; sA[lk4 + h + 1][lr] = av.y;
            sA[lk4 + h + 2][lr] = av.z; sA[lk4 + h + 3][lr] = av.w;
        }
        int bcol = col0 + lnb;
#pragma unroll
        for (int h = 0; h < 32; h += 16) {
            float4 bv = make_float4(0.f, 0.f, 0.f, 0.f);
            if (bcol < N) bv = *(const float4*)(Wm + (size_t)(k0 + lkb + h) * N + bcol);
            *(float4*)&sB[lkb + h][lnb] = bv;
        }
        __syncthreads();

#pragma unroll
        for (int kk2 = 0; kk2 < 32; ++kk2) {
            float4 a = *(const float4*)&sA[kk2][ty * 4];
            float4 bb = *(const float4*)&sB[kk2][tx * 4];
            acc[0][0] = fmaf(a.x, bb.x, acc[0][0]); acc[0][1] = fmaf(a.x, bb.y, acc[0][1]);
            acc[0][2] = fmaf(a.x, bb.z, acc[0][2]); acc[0][3] = fmaf(a.x, bb.w, acc[0][3]);
            acc[1][0] = fmaf(a.y, bb.x, acc[1][0]); acc[1][1] = fmaf(a.y, bb.y, acc[1][1]);
            acc[1][2] = fmaf(a.y, bb.z, acc[1][2]); acc[1][3] = fmaf(a.y, bb.w, acc[1][3]);
            acc[2][0] = fmaf(a.z, bb.x, acc[2][0]); acc[2][1] = fmaf(a.z, bb.y, acc[2][1]);
            acc[2][2] = fmaf(a.z, bb.z, acc[2][2]); acc[2][3] = fmaf(a.z, bb.w, acc[2][3]);
            acc[3][0] = fmaf(a.w, bb.x, acc[3][0]); acc[3][1] = fmaf(a.w, bb.y, acc[3][1]);
            acc[3][2] = fmaf(a.w, bb.z, acc[3][2]); acc[3][3] = fmaf(a.w, bb.w, acc[3][3]);
        }
        __syncthreads();
    }

    for (int i = 0; i < 4; ++i) {
        int row = row0 + ty * 4 + i;
        for (int j = 0; j < 4; ++j) {
            int col = col0 + tx * 4 + j;
            if (col < N) {
                float v = acc[i][j] + bias[col];
                if (leaky) v = v > 0.f ? v : NEG_SLOPE * v;
                Cm[(size_t)row * N + col] = v;
            }
        }
    }
}

// ---------------------------------------------------------------- MFMA GEMM head (bf16 A)
template <int KD, int OUT_BF16>
__global__ __launch_bounds__(256) void gemm_mfma_kernel(const u16* __restrict__ A,
                                                        const u16* __restrict__ BT,
                                                        const float* __restrict__ bias,
                                                        void* __restrict__ Cout,
                                                        int N, int leaky) {
    __shared__ u16 sA[128 * 64];
    __shared__ u16 sB[128 * 64];

    int t = threadIdx.x;
    int wave = t >> 6, lane = t & 63;
    int wm = wave >> 1, wn = wave & 1;
    int row0 = blockIdx.x * 128;
    int col0 = blockIdx.y * 128;

    f32x4 acc[4][4] = {};

    for (int k0 = 0; k0 < KD; k0 += 64) {
        __syncthreads();
#pragma unroll
        for (int i = 0; i < 4; ++i) {
            int li = t + i * 256;
            int r = li >> 3;
            int kc = (li & 7) * 8;
            bf16x8 v = *(const bf16x8*)(A + (size_t)(row0 + r) * KD + k0 + kc);
            *(bf16x8*)((char*)sA + r * 128 + ((kc * 2) ^ ((r & 7) << 4))) = v;
        }
#pragma unroll
        for (int i = 0; i < 4; ++i) {
            int li = t + i * 256;
            int n = li >> 3;
            int kc = (li & 7) * 8;
            bf16x8 v = *(const bf16x8*)(BT + (size_t)(col0 + n) * KD + k0 + kc);
            *(bf16x8*)((char*)sB + n * 128 + ((kc * 2) ^ ((n & 7) << 4))) = v;
        }
        __syncthreads();

#pragma unroll
        for (int kk = 0; kk < 2; ++kk) {
            int kb = kk * 64 + (lane >> 4) * 16;
            bf16x8 af[4], bfr[4];
#pragma unroll
            for (int mi = 0; mi < 4; ++mi) {
                int r = wm * 64 + mi * 16 + (lane & 15);
                af[mi] = *(const bf16x8*)((char*)sA + r * 128 + (kb ^ ((r & 7) << 4)));
            }
#pragma unroll
            for (int ni = 0; ni < 4; ++ni) {
                int n = wn * 64 + ni * 16 + (lane & 15);
                bfr[ni] = *(const bf16x8*)((char*)sB + n * 128 + (kb ^ ((n & 7) << 4)));
            }
#pragma unroll
            for (int mi = 0; mi < 4; ++mi)
#pragma unroll
                for (int ni = 0; ni < 4; ++ni)
                    acc[mi][ni] = __builtin_amdgcn_mfma_f32_16x16x32_bf16(
                        af[mi], bfr[ni], acc[mi][ni], 0, 0, 0);
        }
    }

#pragma unroll
    for (int ni = 0; ni < 4; ++ni) {
        int col = col0 + wn * 64 + ni * 16 + (lane & 15);
        float bs = bias[col];
#pragma unroll
        for (int mi = 0; mi < 4; ++mi) {
#pragma unroll
            for (int r = 0; r < 4; ++r) {
                int row = row0 + wm * 64 + mi * 16 + (lane >> 4) * 4 + r;
                float v = acc[mi][ni][r] + bs;
                if (leaky) v = v > 0.f ? v : NEG_SLOPE * v;
                if (OUT_BF16)
                    ((u16*)Cout)[(size_t)row * N + col] = f2bf(v);
                else
                    ((float*)Cout)[(size_t)row * N + col] = v;
            }
        }
    }
}

// ---------------------------------------------------------------- MFMA GEMM, cat-f32 A (fused cvt)
__global__ __launch_bounds__(256) void gemm_mfma_cat_kernel(const float* __restrict__ x1,
                                                            const float* __restrict__ x2,
                                                            const float* __restrict__ x3,
                                                            const u16* __restrict__ BT,
                                                            const float* __restrict__ bias,
                                                            u16* __restrict__ Cout,
                                                            int N) {
    __shared__ u16 sA[128 * 64];
    __shared__ u16 sB[128 * 64];

    int t = threadIdx.x;
    int wave = t >> 6, lane = t & 63;
    int wm = wave >> 1, wn = wave & 1;
    int row0 = blockIdx.x * 128;
    int col0 = blockIdx.y * 128;

    f32x4 acc[4][4] = {};

#pragma unroll 1
    for (int k0 = 0; k0 < 192; k0 += 64) {
        const float* src = (k0 == 0) ? x1 : (k0 == 64) ? x2 : x3;
        __syncthreads();
#pragma unroll
        for (int i = 0; i < 4; ++i) {
            int li = t + i * 256;
            int r = li >> 3;
            int kc = (li & 7) * 8;
            const float* sp = src + (size_t)(row0 + r) * 64 + kc;
            float4 a0 = *(const float4*)sp;
            float4 a1 = *(const float4*)(sp + 4);
            bf16x8 v;
            v[0] = (short)f2bf(a0.x); v[1] = (short)f2bf(a0.y);
            v[2] = (short)f2bf(a0.z); v[3] = (short)f2bf(a0.w);
            v[4] = (short)f2bf(a1.x); v[5] = (short)f2bf(a1.y);
            v[6] = (short)f2bf(a1.z); v[7] = (short)f2bf(a1.w);
            *(bf16x8*)((char*)sA + r * 128 + ((kc * 2) ^ ((r & 7) << 4))) = v;
        }
#pragma unroll
        for (int i = 0; i < 4; ++i) {
            int li = t + i * 256;
            int n = li >> 3;
            int kc = (li & 7) * 8;
            bf16x8 v = *(const bf16x8*)(BT + (size_t)(col0 + n) * 192 + k0 + kc);
            *(bf16x8*)((char*)sB + n * 128 + ((kc * 2) ^ ((n & 7) << 4))) = v;
        }
        __syncthreads();

#pragma unroll
        for (int kk = 0; kk < 2; ++kk) {
            int kb = kk * 64 + (lane >> 4) * 16;
            bf16x8 af[4], bfr[4];
#pragma unroll
            for (int mi = 0; mi < 4; ++mi) {
                int r = wm * 64 + mi * 16 + (lane & 15);
                af[mi] = *(const bf16x8*)((char*)sA + r * 128 + (kb ^ ((r & 7) << 4)));
            }
#pragma unroll
            for (int ni = 0; ni < 4; ++ni) {
                int n = wn * 64 + ni * 16 + (lane & 15);
                bfr[ni] = *(const bf16x8*)((char*)sB + n * 128 + (kb ^ ((n & 7) << 4)));
            }
#pragma unroll
            for (int mi = 0; mi < 4; ++mi)
#pragma unroll
                for (int ni = 0; ni < 4; ++ni)
                    acc[mi][ni] = __builtin_amdgcn_mfma_f32_16x16x32_bf16(
                        af[mi], bfr[ni], acc[mi][ni], 0, 0, 0);
        }
    }

#pragma unroll
    for (int ni = 0; ni < 4; ++ni) {
        int col = col0 + wn * 64 + ni * 16 + (lane & 15);
        float bs = bias[col];
#pragma unroll
        for (int mi = 0; mi < 4; ++mi) {
#pragma unroll
            for (int r = 0; r < 4; ++r) {
                int row = row0 + wm * 64 + mi * 16 + (lane >> 4) * 4 + r;
                float v = acc[mi][ni][r] + bs;
                v = v > 0.f ? v : NEG_SLOPE * v;
                Cout[(size_t)row * N + col] = f2bf(v);
            }
        }
    }
}

// ---------------------------------------------------------------- fused Wo GEMM + log_softmax
__global__ __launch_bounds__(256) void lsm_wo_kernel(const float* __restrict__ act3,
                                                     const float* __restrict__ Wo,
                                                     const float* __restrict__ bo,
                                                     float* __restrict__ out) {
    __shared__ float sWo[128 * 44];
    __shared__ float sAct[4][128];

    int t = threadIdx.x;
    for (int i = t; i < 128 * 40; i += 256) {
        int k = i / 40, c = i % 40;
        sWo[k * 44 + c] = Wo[i];
    }
    __syncthreads();

    int wv = t >> 6, lane = t & 63;
    int row = blockIdx.x * 4 + wv;
    sAct[wv][lane]      = act3[(size_t)row * 128 + lane];
    sAct[wv][64 + lane] = act3[(size_t)row * 128 + 64 + lane];

    float acc = (lane < C_) ? bo[lane] : -3.4e38f;
    if (lane < C_) {
#pragma unroll 8
        for (int k = 0; k < 128; ++k)
            acc = fmaf(sAct[wv][k], sWo[k * 44 + lane], acc);
    }
    float m = acc;
#pragma unroll
    for (int s = 1; s < 64; s <<= 1) m = fmaxf(m, __shfl_xor(m, s));
    float e = (lane < C_) ? expf(acc - m) : 0.f;
    float sum = e;
#pragma unroll
    for (int s = 1; s < 64; s <<= 1) sum += __shfl_xor(sum, s);
    if (lane < C_) out[(size_t)row * C_ + lane] = acc - m - logf(sum);
}

// ----------------------------------------------------------------
extern "C" void kernel_launch(void* const* d_in, const int* in_sizes, int n_in,
                              void* d_out, int out_size, void* d_ws, size_t ws_size,
                              hipStream_t stream) {
    const float* x   = (const float*)d_in[0];
    const float* W1  = (const float*)d_in[2];
    const float* b1  = (const float*)d_in[3];
    const float* W2  = (const float*)d_in[4];
    const float* b2  = (const float*)d_in[5];
    const float* W3  = (const float*)d_in[6];
    const float* b3  = (const float*)d_in[7];
    const float* Wl  = (const float*)d_in[8];
    const float* bl  = (const float*)d_in[9];
    const float* Wm1 = (const float*)d_in[10];
    const float* bm1 = (const float*)d_in[11];
    const float* Wm2 = (const float*)d_in[12];
    const float* bm2 = (const float*)d_in[13];
    const float* Wo  = (const float*)d_in[14];
    const float* bo  = (const float*)d_in[15];
    float* out = (float*)d_out;

    // ---- workspace (max 50,987,008 B — proven footprint) ----
    char* ws = (char*)d_ws;
    float* x1   = (float*)(ws);
    float* x2   = (float*)(ws + 8388608);
    float* x3   = (float*)(ws + 16777216);
    int*   idx  = (int*)  (ws + 25165824);
    float* d2   = (float*)(ws + 27787264);
    char* hb = ws + 27918336;
    float4* xp  = (float4*)(hb);                      // 512 KB (layer-1 knn; dead before UV)
    u16*   xhs  = (u16*)(hb);                         // 4 MB (layer-2/3 knn)
    u16*   xms  = (u16*)(hb + 4194304);               // 4 MB
    float* UV   = (float*)(hb);                       // 16 MB (edge phase)
    float* Wpk2 = (float*)(ws + 44695552);
    float* bpk2 = (float*)(ws + 44728320);
    float* Wpk3 = (float*)(ws + 44728832);
    float* bpk3 = (float*)(ws + 44761600);
    u16*   WlT  = (u16*)  (ws + 44762112);
    u16*   Wm1T = (u16*)  (ws + 45155328);
    u16*   Wm2T = (u16*)  (ws + 45679616);
    u16*   act1 = (u16*)(hb);
    u16*   act2 = (u16*)(ws + 45745152);
    float* act3 = (float*)(hb);

    prep_kernel<<<1984, 256, 0, stream>>>(W2, b2, W3, b3, Wl, Wm1, Wm2,
                                          Wpk2, bpk2, Wpk3, bpk3, WlT, Wm1T, Wm2T);

    // ---- layer 1 (D=3): barrier-free knn on packed xp
    pack4_kernel<<<NPT / 256, 256, 0, stream>>>(x, xp);
    knnf3_kernel<<<dim3(P_ / 64, B_), 256, 0, stream>>>(xp, idx);
    uv3_kernel<<<NPT * 128 / 256, 256, 0, stream>>>(x, W1, b1, UV);
    edgemax_kernel<<<NPT / 4, 256, 0, stream>>>(UV, idx, x1);
    // ---- layer 2 (D=64)
    d2cvt2_kernel<<<NPT / 256, 256, 0, stream>>>(x1, d2, xhs, xms);
    knnm64_kernel<<<dim3(P_ / 64, B_), 256, 0, stream>>>(xhs, xms, d2, idx);
    gemm_kernel<<<dim3(NPT / 64, 2), 256, 0, stream>>>(x1, Wpk2, bpk2, UV, NPT, 128, 64, 0);
    edgemax_kernel<<<NPT / 4, 256, 0, stream>>>(UV, idx, x2);
    // ---- layer 3 (D=64)
    d2cvt2_kernel<<<NPT / 256, 256, 0, stream>>>(x2, d2, xhs, xms);
    knnm64_kernel<<<dim3(P_ / 64, B_), 256, 0, stream>>>(xhs, xms, d2, idx);
    gemm_kernel<<<dim3(NPT / 64, 2), 256, 0, stream>>>(x2, Wpk3, bpk3, UV, NPT, 128, 64, 0);
    edgemax_kernel<<<NPT / 4, 256, 0, stream>>>(UV, idx, x3);

    // ---- MLP head: 4 chunks of 8192 rows
    for (int c = 0; c < 4; ++c) {
        size_t r0 = (size_t)c * 8192;
        gemm_mfma_cat_kernel<<<dim3(64, 8), 256, 0, stream>>>(x1 + r0 * 64, x2 + r0 * 64,
                                                              x3 + r0 * 64, WlT, bl, act1, 1024);
        gemm_mfma_kernel<1024, 1><<<dim3(64, 2), 256, 0, stream>>>(act1, Wm1T, bm1, act2, 256, 1);
        gemm_mfma_kernel<256, 0><<<dim3(64, 1), 256, 0, stream>>>(act2, Wm2T, bm2, act3, 128, 1);
        lsm_wo_kernel<<<2048, 256, 0, stream>>>(act3, Wo, bo, out + r0 * C_);
    }
}

// Round 21
// 880.068 us; speedup vs baseline: 1.1265x; 1.0102x over previous
//
#include <hip/hip_runtime.h>
#include <cstddef>
#include <cstdint>

constexpr int B_ = 8, P_ = 4096, K_ = 20, H_ = 64, C_ = 40;
constexpr int NPT = B_ * P_;
#define NEG_SLOPE 0.2f

typedef unsigned long long u64;
typedef unsigned int u32;
typedef unsigned short u16;
typedef __attribute__((ext_vector_type(8))) short bf16x8;
typedef __attribute__((ext_vector_type(4))) float f32x4;

__device__ inline u16 f2bf(float v) {   // round-to-nearest-even bf16
    u32 bits = __float_as_uint(v);
    return (u16)((bits + 0x7FFFu + ((bits >> 16) & 1)) >> 16);
}
__device__ inline float bf2f(u16 h) { return __uint_as_float((u32)h << 16); }

// sorted-ascending 20-slot bubble insert, f32 keys (positive, bit-ordered)
__device__ __forceinline__ void bubble20f(float (&a)[K_], float key) {
    float carry = key;
#pragma unroll
    for (int s = 0; s < K_; ++s) {
        float as = a[s];
        a[s]  = fminf(carry, as);
        carry = fmaxf(carry, as);
    }
}
// key = (dist_bits & ~0xFFF) | cid   (cid < 4096; dist >= 0 finite)
__device__ __forceinline__ float mkkey(float dist, int cid) {
    return __uint_as_float((__float_as_uint(dist) & 0xFFFFF000u) | (u32)cid);
}

// ---------------------------------------------------------------- pack x -> (x,y,z,d2) float4
__global__ __launch_bounds__(256) void pack4_kernel(const float* __restrict__ x,
                                                    float4* __restrict__ xp) {
    int i = blockIdx.x * 256 + threadIdx.x;
    if (i >= NPT) return;
    float ax = x[(size_t)i * 3], ay = x[(size_t)i * 3 + 1], az = x[(size_t)i * 3 + 2];
    xp[i] = make_float4(ax, ay, az, ax * ax + ay * ay + az * az);
}

// ---------------------------------------------------------------- fused d2 + h/m split (D=64)
__global__ __launch_bounds__(256) void d2cvt2_kernel(const float* __restrict__ x,
                                                     float* __restrict__ d2,
                                                     u16* __restrict__ xh,
                                                     u16* __restrict__ xm) {
    int i = blockIdx.x * 256 + threadIdx.x;
    if (i >= NPT) return;
    const float* r = x + (size_t)i * 64;
    float s = 0.f;
#pragma unroll
    for (int d8 = 0; d8 < 64; d8 += 8) {
        float4 v0 = *(const float4*)(r + d8);
        float4 v1 = *(const float4*)(r + d8 + 4);
        s += v0.x * v0.x + v0.y * v0.y + v0.z * v0.z + v0.w * v0.w;
        s += v1.x * v1.x + v1.y * v1.y + v1.z * v1.z + v1.w * v1.w;
        float av[8] = {v0.x, v0.y, v0.z, v0.w, v1.x, v1.y, v1.z, v1.w};
        bf16x8 vh, vm;
#pragma unroll
        for (int j = 0; j < 8; ++j) {
            u16 h = f2bf(av[j]);
            float r1 = av[j] - bf2f(h);
            vh[j] = (short)h; vm[j] = (short)f2bf(r1);
        }
        *(bf16x8*)(xh + (size_t)i * 64 + d8) = vh;
        *(bf16x8*)(xm + (size_t)i * 64 + d8) = vm;
    }
    d2[i] = s;
}

// ---------------------------------------------------------------- layer-1 knn (D=3): barrier-free,
// LDS-free; candidates loaded directly from L2-resident packed xp (16-lane broadcast).
__global__ __launch_bounds__(256) void knnf3_kernel(const float4* __restrict__ xp,
                                                    int* __restrict__ idx) {
    int b = blockIdx.y;
    int q0 = blockIdx.x * 64;
    const float4* xb = xp + (size_t)b * P_;

    int t = threadIdx.x, w = t >> 6, ln = t & 63;
    int q  = ln & 15;
    int ss = ln >> 4;

    int qrow = q0 + w * 16 + q;
    float4 qv = xb[qrow];

    float a[K_];
#pragma unroll
    for (int s = 0; s < K_; ++s)
        a[s] = __uint_as_float(0x7F7FF000u | (u32)s);    // distinct huge finite sentinels
    const float PINV = __uint_as_float(0x7F800000u);     // +inf
    const float BIGF = __uint_as_float(0x7F7FFFFFu);     // FLT_MAX

    float p0 = PINV, p1 = PINV, p2 = PINV, p3 = PINV;
    int pcnt = 0;
    float kthr = BIGF;

#pragma unroll 1
    for (int c0 = 0; c0 < P_; c0 += 64) {
#pragma unroll
        for (int nt = 0; nt < 4; ++nt) {
            float4 cv[4];
#pragma unroll
            for (int r = 0; r < 4; ++r)
                cv[r] = xb[c0 + nt * 16 + ss * 4 + r];
#pragma unroll
            for (int r = 0; r < 4; ++r) {
                int cID = c0 + nt * 16 + ss * 4 + r;
                float dv = (qv.w + cv[r].w)
                         - 2.f * (qv.x * cv[r].x + qv.y * cv[r].y + qv.z * cv[r].z);
                if (cID == qrow) dv += 1e10f;
                dv = fmaxf(dv, 0.f);
                if (__any(dv <= kthr)) {
                    float key = mkkey(dv, cID);
                    bool pass = key < a[K_ - 1];
                    p3 = pass ? p2 : p3;
                    p2 = pass ? p1 : p2;
                    p1 = pass ? p0 : p1;
                    p0 = pass ? key : p0;
                    pcnt = pass ? pcnt + 1 : pcnt;
                    if (__any(pcnt >= 4)) {
                        bubble20f(a, p3); bubble20f(a, p2); bubble20f(a, p1); bubble20f(a, p0);
                        p0 = p1 = p2 = p3 = PINV; pcnt = 0;
                        kthr = __uint_as_float(__float_as_uint(a[K_ - 1]) | 0xFFFu);
                    }
                }
            }
        }
    }
    bubble20f(a, p3); bubble20f(a, p2); bubble20f(a, p1); bubble20f(a, p0);

    int* op = idx + ((size_t)(b * P_ + qrow)) * K_;
#pragma unroll 1
    for (int k = 0; k < K_; ++k) {
        float v = a[0];
        float v1 = __shfl_xor(v, 16);
        v = fminf(v, v1);
        float v2 = __shfl_xor(v, 32);
        v = fminf(v, v2);
        bool win = (__float_as_uint(a[0]) == __float_as_uint(v));
#pragma unroll
        for (int s = 0; s < K_ - 1; ++s) a[s] = win ? a[s + 1] : a[s];
        a[K_ - 1] = win ? BIGF : a[K_ - 1];
        if (ss == 0)
            op[k] = b * P_ + (int)(__float_as_uint(v) & 0xFFFu);
    }
}

// ---------------------------------------------------------------- fused knn (D=64) via MFMA, 3-product h/m
// Chunk-64, full sd2[P_] stage (R19-proven configuration).
__global__ __launch_bounds__(256) void knnm64_kernel(const u16* __restrict__ xh,
                                                     const u16* __restrict__ xm,
                                                     const float* __restrict__ d2,
                                                     int* __restrict__ idx) {
    __shared__ u16 sH[64 * 64];      // elem (r,k) at byte r*128 + ((k*2) ^ ((r&7)<<4))
    __shared__ u16 sM[64 * 64];
    __shared__ float sd2[P_];        // 16 KB

    int b = blockIdx.y;
    int q0 = blockIdx.x * 64;
    const u16* xhb = xh + (size_t)b * P_ * 64;
    const u16* xmb = xm + (size_t)b * P_ * 64;
    const float* d2b = d2 + (size_t)b * P_;

    int t = threadIdx.x, w = t >> 6, ln = t & 63;
    int q  = ln & 15;
    int ss = ln >> 4;

    for (int i = t; i < P_ / 4; i += 256)
        ((float4*)sd2)[i] = ((const float4*)d2b)[i];

    int qrow = q0 + w * 16 + q;
    bf16x8 qh[2], qm[2];
#pragma unroll
    for (int kt = 0; kt < 2; ++kt) {
        size_t off = (size_t)qrow * 64 + kt * 32 + ss * 8;
        qh[kt] = *(const bf16x8*)(xhb + off);
        qm[kt] = *(const bf16x8*)(xmb + off);
    }

    __syncthreads();
    float qd2 = sd2[qrow];

    float a[K_];
#pragma unroll
    for (int s = 0; s < K_; ++s)
        a[s] = __uint_as_float(0x7F7FF000u | (u32)s);
    const float PINV = __uint_as_float(0x7F800000u);     // +inf
    const float BIGF = __uint_as_float(0x7F7FFFFFu);     // FLT_MAX

    float p0 = PINV, p1 = PINV, p2 = PINV, p3 = PINV;
    int pcnt = 0;
    float kthr = BIGF;

    int sr = t >> 2;
    int sk2 = (t & 3) * 32;
    int sbase = sr * 128, sswz = (sr & 7) << 4;
    size_t sgof = (size_t)sr * 64 + (t & 3) * 16;

#pragma unroll 1
    for (int c0 = 0; c0 < P_; c0 += 64) {
        __syncthreads();
        {
            size_t g = (size_t)c0 * 64 + sgof;
            bf16x8 h0 = *(const bf16x8*)(xhb + g);
            bf16x8 h1 = *(const bf16x8*)(xhb + g + 8);
            bf16x8 m0 = *(const bf16x8*)(xmb + g);
            bf16x8 m1 = *(const bf16x8*)(xmb + g + 8);
            *(bf16x8*)((char*)sH + sbase + (sk2 ^ sswz)) = h0;
            *(bf16x8*)((char*)sH + sbase + ((sk2 + 16) ^ sswz)) = h1;
            *(bf16x8*)((char*)sM + sbase + (sk2 ^ sswz)) = m0;
            *(bf16x8*)((char*)sM + sbase + ((sk2 + 16) ^ sswz)) = m1;
        }
        __syncthreads();

        f32x4 acc[4];
#pragma unroll
        for (int nt = 0; nt < 4; ++nt) {
            acc[nt] = (f32x4){0.f, 0.f, 0.f, 0.f};
            int r = nt * 16 + q;
            int base = r * 128, swz = (r & 7) << 4;
#pragma unroll
            for (int kt = 0; kt < 2; ++kt) {
                int k2 = kt * 64 + ss * 16;
                bf16x8 ch = *(const bf16x8*)((char*)sH + base + (k2 ^ swz));
                bf16x8 cm = *(const bf16x8*)((char*)sM + base + (k2 ^ swz));
                // 3-product split: hh + hm + mh
                acc[nt] = __builtin_amdgcn_mfma_f32_16x16x32_bf16(cm, qh[kt], acc[nt], 0, 0, 0);
                acc[nt] = __builtin_amdgcn_mfma_f32_16x16x32_bf16(ch, qm[kt], acc[nt], 0, 0, 0);
                acc[nt] = __builtin_amdgcn_mfma_f32_16x16x32_bf16(ch, qh[kt], acc[nt], 0, 0, 0);
            }
        }

        float dvv[4][4];
        float mn = 3.4e38f;
#pragma unroll
        for (int nt = 0; nt < 4; ++nt) {
#pragma unroll
            for (int r = 0; r < 4; ++r) {
                int cID = c0 + nt * 16 + ss * 4 + r;
                float dv = (qd2 + sd2[cID]) - 2.f * acc[nt][r];
                if (cID == qrow) dv += 1e10f;
                dv = fmaxf(dv, 0.f);
                dvv[nt][r] = dv;
                mn = fminf(mn, dv);
            }
        }
        if (__any(mn <= kthr)) {
#pragma unroll
            for (int nt = 0; nt < 4; ++nt) {
#pragma unroll
                for (int r = 0; r < 4; ++r) {
                    float dv = dvv[nt][r];
                    if (__any(dv <= kthr)) {
                        float key = mkkey(dv, c0 + nt * 16 + ss * 4 + r);
                        bool pass = key < a[K_ - 1];
                        p3 = pass ? p2 : p3;
                        p2 = pass ? p1 : p2;
                        p1 = pass ? p0 : p1;
                        p0 = pass ? key : p0;
                        pcnt = pass ? pcnt + 1 : pcnt;
                        if (__any(pcnt >= 4)) {
                            bubble20f(a, p3); bubble20f(a, p2); bubble20f(a, p1); bubble20f(a, p0);
                            p0 = p1 = p2 = p3 = PINV; pcnt = 0;
                            kthr = __uint_as_float(__float_as_uint(a[K_ - 1]) | 0xFFFu);
                        }
                    }
                }
            }
        }
    }
    bubble20f(a, p3); bubble20f(a, p2); bubble20f(a, p1); bubble20f(a, p0);

    int* op = idx + ((size_t)(b * P_ + qrow)) * K_;
#pragma unroll 1
    for (int k = 0; k < K_; ++k) {
        float v = a[0];
        float v1 = __shfl_xor(v, 16);
        v = fminf(v, v1);
        float v2 = __shfl_xor(v, 32);
        v = fminf(v, v2);
        bool win = (__float_as_uint(a[0]) == __float_as_uint(v));
#pragma unroll
        for (int s = 0; s < K_ - 1; ++s) a[s] = win ? a[s + 1] : a[s];
        a[K_ - 1] = win ? BIGF : a[K_ - 1];
        if (ss == 0)
            op[k] = b * P_ + (int)(__float_as_uint(v) & 0xFFFu);
    }
}

// ---------------------------------------------------------------- one-shot weight prep
__global__ __launch_bounds__(256) void prep_kernel(const float* __restrict__ W2,
                                                   const float* __restrict__ b2,
                                                   const float* __restrict__ W3,
                                                   const float* __restrict__ b3,
                                                   const float* __restrict__ Wl,
                                                   const float* __restrict__ Wm1,
                                                   const float* __restrict__ Wm2,
                                                   float* __restrict__ Wpk2, float* __restrict__ bpk2,
                                                   float* __restrict__ Wpk3, float* __restrict__ bpk3,
                                                   u16* __restrict__ WlT,
                                                   u16* __restrict__ Wm1T,
                                                   u16* __restrict__ Wm2T) {
    int t = blockIdx.x * 256 + threadIdx.x;
    if (t < 8192) {
        int d = t >> 7, h2 = t & 127;
        Wpk2[t] = (h2 < 64) ? W2[d * 64 + h2] : W2[(64 + d) * 64 + (h2 - 64)];
        if (t < 128) bpk2[t] = (t < 64) ? b2[t] : 0.f;
    } else if (t < 16384) {
        int t2 = t - 8192;
        int d = t2 >> 7, h2 = t2 & 127;
        Wpk3[t2] = (h2 < 64) ? W3[d * 64 + h2] : W3[(64 + d) * 64 + (h2 - 64)];
        if (t2 < 128) bpk3[t2] = (t2 < 64) ? b3[t2] : 0.f;
    } else if (t < 212992) {
        int t2 = t - 16384;
        int k = t2 >> 10, n = t2 & 1023;
        WlT[(size_t)n * 192 + k] = f2bf(Wl[t2]);
    } else if (t < 475136) {
        int t2 = t - 212992;
        int k = t2 >> 8, n = t2 & 255;
        Wm1T[(size_t)n * 1024 + k] = f2bf(Wm1[t2]);
    } else if (t < 507904) {
        int t2 = t - 475136;
        int k = t2 >> 7, n = t2 & 127;
        Wm2T[(size_t)n * 256 + k] = f2bf(Wm2[t2]);
    }
}

// ---------------------------------------------------------------- layer-1 UV (D=3, direct)
__global__ __launch_bounds__(256) void uv3_kernel(const float* __restrict__ x,
                                                  const float* __restrict__ W,
                                                  const float* __restrict__ b,
                                                  float* __restrict__ UV) {
    int t = blockIdx.x * 256 + threadIdx.x;
    int p = t >> 7, h2 = t & 127;
    float x0 = x[p * 3], x1 = x[p * 3 + 1], x2 = x[p * 3 + 2];
    float r;
    if (h2 < 64) {
        r = b[h2] + x0 * W[h2] + x1 * W[64 + h2] + x2 * W[128 + h2];
    } else {
        int h = h2 - 64;
        r = x0 * W[192 + h] + x1 * W[256 + h] + x2 * W[320 + h];
    }
    UV[t] = r;
}

// ---------------------------------------------------------------- edge max
__global__ __launch_bounds__(256) void edgemax_kernel(const float* __restrict__ UV,
                                                      const int* __restrict__ idx,
                                                      float* __restrict__ xout) {
    int wv = threadIdx.x >> 6, lane = threadIdx.x & 63;
    int p = blockIdx.x * 4 + wv;
    const float* uvp = UV + (size_t)p * 128;
    float duv = uvp[lane] - uvp[64 + lane];
    const int* ip = idx + (size_t)p * K_;
    int jj[K_];
#pragma unroll
    for (int k = 0; k < K_; ++k) jj[k] = ip[k];
    float m = -3.4e38f;
#pragma unroll
    for (int k = 0; k < K_; ++k) {
        float vj = UV[(size_t)jj[k] * 128 + 64 + lane];
        float t = duv + vj;
        m = fmaxf(m, fmaxf(t, NEG_SLOPE * t));
    }
    xout[(size_t)p * H_ + lane] = m;
}

// ---------------------------------------------------------------- GEMM 64x64 f32 (UV)
__global__ __launch_bounds__(256) void gemm_kernel(const float* __restrict__ A1,
                                                   const float* __restrict__ Wm,
                                                   const float* __restrict__ bias,
                                                   float* __restrict__ Cm,
                                                   int M, int N, int Kd, int leaky) {
    __shared__ float sA[32][68];
    __shared__ float sB[32][68];

    int tid = threadIdx.x;
    int row0 = blockIdx.x * 64, col0 = blockIdx.y * 64;
    int tx = tid & 15, ty = tid >> 4;

    int lr  = tid >> 2;
    int lk4 = (tid & 3) * 4;
    int lkb = tid >> 4;
    int lnb = (tid & 15) * 4;

    float acc[4][4] = {};

    for (int k0 = 0; k0 < Kd; k0 += 32) {
        int arow = row0 + lr;
#pragma unroll
        for (int h = 0; h < 32; h += 16) {
            int kk = k0 + lk4 + h;
            const float* src = A1 + (size_t)arow * Kd + kk;
            float4 av = *(const float4*)src;
            sA[lk4 + h + 0][lr] = av.x; sA[lk4 + h + 1][lr] = av.y;
            sA[lk4 + h + 2][lr] = av.z; sA[lk4 + h + 3][lr] = av.w;
        }
        int bcol = col0 + lnb;
#pragma unroll
        for (int h = 0; h < 32; h += 16) {
            float4 bv = make_float4(0.f, 0.f, 0.f, 0.f);
            if (bcol < N) bv = *(const float4*)(Wm + (size_t)(k0 + lkb + h) * N + bcol);
            *(float4*)&sB[lkb + h][lnb] = bv;
        }
        __syncthreads();

#pragma unroll
        for (int kk2 = 0; kk2 < 32; ++kk2) {
            float4 a = *(const float4*)&sA[kk2][ty * 4];
            float4 bb = *(const float4*)&sB[kk2][tx * 4];
            acc[0][0] = fmaf(a.x, bb.x, acc[0][0]); acc[0][1] = fmaf(a.x, bb.y, acc[0][1]);
            acc[0][2] = fmaf(a.x, bb.z, acc[0][2]); acc[0][3] = fmaf(a.x, bb.w, acc[0][3]);
            acc[1][0] = fmaf(a.y, bb.x, acc[1][0]); acc[1][1] = fmaf(a.y, bb.y, acc[1][1]);
            acc[1][2] = fmaf(a.y, bb.z, acc[1][2]); acc[1][3] = fmaf(a.y, bb.w, acc[1][3]);
            acc[2][0] = fmaf(a.z, bb.x, acc[2][0]); acc[2][1] = fmaf(a.z, bb.y, acc[2][1]);
            acc[2][2] = fmaf(a.z, bb.z, acc[2][2]); acc[2][3] = fmaf(a.z, bb.w, acc[2][3]);
            acc[3][0] = fmaf(a.w, bb.x, acc[3][0]); acc[3][1] = fmaf(a.w, bb.y, acc[3][1]);
            acc[3][2] = fmaf(a.w, bb.z, acc[3][2]); acc[3][3] = fmaf(a.w, bb.w, acc[3][3]);
        }
        __syncthreads();
    }

    for (int i = 0; i < 4; ++i) {
        int row = row0 + ty * 4 + i;
        for (int j = 0; j < 4; ++j) {
            int col = col0 + tx * 4 + j;
            if (col < N) {
                float v = acc[i][j] + bias[col];
                if (leaky) v = v > 0.f ? v : NEG_SLOPE * v;
                Cm[(size_t)row * N + col] = v;
            }
        }
    }
}

// ---------------------------------------------------------------- MFMA GEMM head (bf16 A)
template <int KD, int OUT_BF16>
__global__ __launch_bounds__(256) void gemm_mfma_kernel(const u16* __restrict__ A,
                                                        const u16* __restrict__ BT,
                                                        const float* __restrict__ bias,
                                                        void* __restrict__ Cout,
                                                        int N, int leaky) {
    __shared__ u16 sA[128 * 64];
    __shared__ u16 sB[128 * 64];

    int t = threadIdx.x;
    int wave = t >> 6, lane = t & 63;
    int wm = wave >> 1, wn = wave & 1;
    int row0 = blockIdx.x * 128;
    int col0 = blockIdx.y * 128;

    f32x4 acc[4][4] = {};

    for (int k0 = 0; k0 < KD; k0 += 64) {
        __syncthreads();
#pragma unroll
        for (int i = 0; i < 4; ++i) {
            int li = t + i * 256;
            int r = li >> 3;
            int kc = (li & 7) * 8;
            bf16x8 v = *(const bf16x8*)(A + (size_t)(row0 + r) * KD + k0 + kc);
            *(bf16x8*)((char*)sA + r * 128 + ((kc * 2) ^ ((r & 7) << 4))) = v;
        }
#pragma unroll
        for (int i = 0; i < 4; ++i) {
            int li = t + i * 256;
            int n = li >> 3;
            int kc = (li & 7) * 8;
            bf16x8 v = *(const bf16x8*)(BT + (size_t)(col0 + n) * KD + k0 + kc);
            *(bf16x8*)((char*)sB + n * 128 + ((kc * 2) ^ ((n & 7) << 4))) = v;
        }
        __syncthreads();

#pragma unroll
        for (int kk = 0; kk < 2; ++kk) {
            int kb = kk * 64 + (lane >> 4) * 16;
            bf16x8 af[4], bfr[4];
#pragma unroll
            for (int mi = 0; mi < 4; ++mi) {
                int r = wm * 64 + mi * 16 + (lane & 15);
                af[mi] = *(const bf16x8*)((char*)sA + r * 128 + (kb ^ ((r & 7) << 4)));
            }
#pragma unroll
            for (int ni = 0; ni < 4; ++ni) {
                int n = wn * 64 + ni * 16 + (lane & 15);
                bfr[ni] = *(const bf16x8*)((char*)sB + n * 128 + (kb ^ ((n & 7) << 4)));
            }
#pragma unroll
            for (int mi = 0; mi < 4; ++mi)
#pragma unroll
                for (int ni = 0; ni < 4; ++ni)
                    acc[mi][ni] = __builtin_amdgcn_mfma_f32_16x16x32_bf16(
                        af[mi], bfr[ni], acc[mi][ni], 0, 0, 0);
        }
    }

#pragma unroll
    for (int ni = 0; ni < 4; ++ni) {
        int col = col0 + wn * 64 + ni * 16 + (lane & 15);
        float bs = bias[col];
#pragma unroll
        for (int mi = 0; mi < 4; ++mi) {
#pragma unroll
            for (int r = 0; r < 4; ++r) {
                int row = row0 + wm * 64 + mi * 16 + (lane >> 4) * 4 + r;
                float v = acc[mi][ni][r] + bs;
                if (leaky) v = v > 0.f ? v : NEG_SLOPE * v;
                if (OUT_BF16)
                    ((u16*)Cout)[(size_t)row * N + col] = f2bf(v);
                else
                    ((float*)Cout)[(size_t)row * N + col] = v;
            }
        }
    }
}

// ---------------------------------------------------------------- MFMA GEMM, cat-f32 A (fused cvt)
__global__ __launch_bounds__(256) void gemm_mfma_cat_kernel(const float* __restrict__ x1,
                                                            const float* __restrict__ x2,
                                                            const float* __restrict__ x3,
                                                            const u16* __restrict__ BT,
                                                            const float* __restrict__ bias,
                                                            u16* __restrict__ Cout,
                                                            int N) {
    __shared__ u16 sA[128 * 64];
    __shared__ u16 sB[128 * 64];

    int t = threadIdx.x;
    int wave = t >> 6, lane = t & 63;
    int wm = wave >> 1, wn = wave & 1;
    int row0 = blockIdx.x * 128;
    int col0 = blockIdx.y * 128;

    f32x4 acc[4][4] = {};

#pragma unroll 1
    for (int k0 = 0; k0 < 192; k0 += 64) {
        const float* src = (k0 == 0) ? x1 : (k0 == 64) ? x2 : x3;
        __syncthreads();
#pragma unroll
        for (int i = 0; i < 4; ++i) {
            int li = t + i * 256;
            int r = li >> 3;
            int kc = (li & 7) * 8;
            const float* sp = src + (size_t)(row0 + r) * 64 + kc;
            float4 a0 = *(const float4*)sp;
            float4 a1 = *(const float4*)(sp + 4);
            bf16x8 v;
            v[0] = (short)f2bf(a0.x); v[1] = (short)f2bf(a0.y);
            v[2] = (short)f2bf(a0.z); v[3] = (short)f2bf(a0.w);
            v[4] = (short)f2bf(a1.x); v[5] = (short)f2bf(a1.y);
            v[6] = (short)f2bf(a1.z); v[7] = (short)f2bf(a1.w);
            *(bf16x8*)((char*)sA + r * 128 + ((kc * 2) ^ ((r & 7) << 4))) = v;
        }
#pragma unroll
        for (int i = 0; i < 4; ++i) {
            int li = t + i * 256;
            int n = li >> 3;
            int kc = (li & 7) * 8;
            bf16x8 v = *(const bf16x8*)(BT + (size_t)(col0 + n) * 192 + k0 + kc);
            *(bf16x8*)((char*)sB + n * 128 + ((kc * 2) ^ ((n & 7) << 4))) = v;
        }
        __syncthreads();

#pragma unroll
        for (int kk = 0; kk < 2; ++kk) {
            int kb = kk * 64 + (lane >> 4) * 16;
            bf16x8 af[4], bfr[4];
#pragma unroll
            for (int mi = 0; mi < 4; ++mi) {
                int r = wm * 64 + mi * 16 + (lane & 15);
                af[mi] = *(const bf16x8*)((char*)sA + r * 128 + (kb ^ ((r & 7) << 4)));
            }
#pragma unroll
            for (int ni = 0; ni < 4; ++ni) {
                int n = wn * 64 + ni * 16 + (lane & 15);
                bfr[ni] = *(const bf16x8*)((char*)sB + n * 128 + (kb ^ ((n & 7) << 4)));
            }
#pragma unroll
            for (int mi = 0; mi < 4; ++mi)
#pragma unroll
                for (int ni = 0; ni < 4; ++ni)
                    acc[mi][ni] = __builtin_amdgcn_mfma_f32_16x16x32_bf16(
                        af[mi], bfr[ni], acc[mi][ni], 0, 0, 0);
        }
    }

#pragma unroll
    for (int ni = 0; ni < 4; ++ni) {
        int col = col0 + wn * 64 + ni * 16 + (lane & 15);
        float bs = bias[col];
#pragma unroll
        for (int mi = 0; mi < 4; ++mi) {
#pragma unroll
            for (int r = 0; r < 4; ++r) {
                int row = row0 + wm * 64 + mi * 16 + (lane >> 4) * 4 + r;
                float v = acc[mi][ni][r] + bs;
                v = v > 0.f ? v : NEG_SLOPE * v;
                Cout[(size_t)row * N + col] = f2bf(v);
            }
        }
    }
}

// ---------------------------------------------------------------- fused Wo GEMM + log_softmax
__global__ __launch_bounds__(256) void lsm_wo_kernel(const float* __restrict__ act3,
                                                     const float* __restrict__ Wo,
                                                     const float* __restrict__ bo,
                                                     float* __restrict__ out) {
    __shared__ float sWo[128 * 44];
    __shared__ float sAct[4][128];

    int t = threadIdx.x;
    for (int i = t; i < 128 * 40; i += 256) {
        int k = i / 40, c = i % 40;
        sWo[k * 44 + c] = Wo[i];
    }
    __syncthreads();

    int wv = t >> 6, lane = t & 63;
    int row = blockIdx.x * 4 + wv;
    sAct[wv][lane]      = act3[(size_t)row * 128 + lane];
    sAct[wv][64 + lane] = act3[(size_t)row * 128 + 64 + lane];

    float acc = (lane < C_) ? bo[lane] : -3.4e38f;
    if (lane < C_) {
#pragma unroll 8
        for (int k = 0; k < 128; ++k)
            acc = fmaf(sAct[wv][k], sWo[k * 44 + lane], acc);
    }
    float m = acc;
#pragma unroll
    for (int s = 1; s < 64; s <<= 1) m = fmaxf(m, __shfl_xor(m, s));
    float e = (lane < C_) ? expf(acc - m) : 0.f;
    float sum = e;
#pragma unroll
    for (int s = 1; s < 64; s <<= 1) sum += __shfl_xor(sum, s);
    if (lane < C_) out[(size_t)row * C_ + lane] = acc - m - logf(sum);
}

// ----------------------------------------------------------------
extern "C" void kernel_launch(void* const* d_in, const int* in_sizes, int n_in,
                              void* d_out, int out_size, void* d_ws, size_t ws_size,
                              hipStream_t stream) {
    const float* x   = (const float*)d_in[0];
    const float* W1  = (const float*)d_in[2];
    const float* b1  = (const float*)d_in[3];
    const float* W2  = (const float*)d_in[4];
    const float* b2  = (const float*)d_in[5];
    const float* W3  = (const float*)d_in[6];
    const float* b3  = (const float*)d_in[7];
    const float* Wl  = (const float*)d_in[8];
    const float* bl  = (const float*)d_in[9];
    const float* Wm1 = (const float*)d_in[10];
    const float* bm1 = (const float*)d_in[11];
    const float* Wm2 = (const float*)d_in[12];
    const float* bm2 = (const float*)d_in[13];
    const float* Wo  = (const float*)d_in[14];
    const float* bo  = (const float*)d_in[15];
    float* out = (float*)d_out;

    // ---- workspace (max 50,987,008 B — proven footprint) ----
    char* ws = (char*)d_ws;
    float* x1   = (float*)(ws);
    float* x2   = (float*)(ws + 8388608);
    float* x3   = (float*)(ws + 16777216);
    int*   idx  = (int*)  (ws + 25165824);
    float* d2   = (float*)(ws + 27787264);
    char* hb = ws + 27918336;
    float4* xp  = (float4*)(hb);                      // 512 KB (layer-1 knn; dead before UV)
    u16*   xhs  = (u16*)(hb);                         // 4 MB (layer-2/3 knn)
    u16*   xms  = (u16*)(hb + 4194304);               // 4 MB
    float* UV   = (float*)(hb);                       // 16 MB (edge phase)
    float* Wpk2 = (float*)(ws + 44695552);
    float* bpk2 = (float*)(ws + 44728320);
    float* Wpk3 = (float*)(ws + 44728832);
    float* bpk3 = (float*)(ws + 44761600);
    u16*   WlT  = (u16*)  (ws + 44762112);
    u16*   Wm1T = (u16*)  (ws + 45155328);
    u16*   Wm2T = (u16*)  (ws + 45679616);
    u16*   act1 = (u16*)(hb);
    u16*   act2 = (u16*)(ws + 45745152);
    float* act3 = (float*)(hb);

    prep_kernel<<<1984, 256, 0, stream>>>(W2, b2, W3, b3, Wl, Wm1, Wm2,
                                          Wpk2, bpk2, Wpk3, bpk3, WlT, Wm1T, Wm2T);

    // ---- layer 1 (D=3): barrier-free knn on packed xp
    pack4_kernel<<<NPT / 256, 256, 0, stream>>>(x, xp);
    knnf3_kernel<<<dim3(P_ / 64, B_), 256, 0, stream>>>(xp, idx);
    uv3_kernel<<<NPT * 128 / 256, 256, 0, stream>>>(x, W1, b1, UV);
    edgemax_kernel<<<NPT / 4, 256, 0, stream>>>(UV, idx, x1);
    // ---- layer 2 (D=64)
    d2cvt2_kernel<<<NPT / 256, 256, 0, stream>>>(x1, d2, xhs, xms);
    knnm64_kernel<<<dim3(P_ / 64, B_), 256, 0, stream>>>(xhs, xms, d2, idx);
    gemm_kernel<<<dim3(NPT / 64, 2), 256, 0, stream>>>(x1, Wpk2, bpk2, UV, NPT, 128, 64, 0);
    edgemax_kernel<<<NPT / 4, 256, 0, stream>>>(UV, idx, x2);
    // ---- layer 3 (D=64)
    d2cvt2_kernel<<<NPT / 256, 256, 0, stream>>>(x2, d2, xhs, xms);
    knnm64_kernel<<<dim3(P_ / 64, B_), 256, 0, stream>>>(xhs, xms, d2, idx);
    gemm_kernel<<<dim3(NPT / 64, 2), 256, 0, stream>>>(x2, Wpk3, bpk3, UV, NPT, 128, 64, 0);
    edgemax_kernel<<<NPT / 4, 256, 0, stream>>>(UV, idx, x3);

    // ---- MLP head: 4 chunks of 8192 rows
    for (int c = 0; c < 4; ++c) {
        size_t r0 = (size_t)c * 8192;
        gemm_mfma_cat_kernel<<<dim3(64, 8), 256, 0, stream>>>(x1 + r0 * 64, x2 + r0 * 64,
                                                              x3 + r0 * 64, WlT, bl, act1, 1024);
        gemm_mfma_kernel<1024, 1><<<dim3(64, 2), 256, 0, stream>>>(act1, Wm1T, bm1, act2, 256, 1);
        gemm_mfma_kernel<256, 0><<<dim3(64, 1), 256, 0, stream>>>(act2, Wm2T, bm2, act3, 128, 1);
        lsm_wo_kernel<<<2048, 256, 0, stream>>>(act3, Wo, bo, out + r0 * C_);
    }
}

// Round 22
// 871.876 us; speedup vs baseline: 1.1371x; 1.0094x over previous
//
#include <hip/hip_runtime.h>
#include <cstddef>
#include <cstdint>

constexpr int B_ = 8, P_ = 4096, K_ = 20, H_ = 64, C_ = 40;
constexpr int NPT = B_ * P_;
constexpr int HALF = P_ / 2;
#define NEG_SLOPE 0.2f

typedef unsigned long long u64;
typedef unsigned int u32;
typedef unsigned short u16;
typedef __attribute__((ext_vector_type(8))) short bf16x8;
typedef __attribute__((ext_vector_type(4))) float f32x4;

__device__ inline u16 f2bf(float v) {   // round-to-nearest-even bf16
    u32 bits = __float_as_uint(v);
    return (u16)((bits + 0x7FFFu + ((bits >> 16) & 1)) >> 16);
}
__device__ inline float bf2f(u16 h) { return __uint_as_float((u32)h << 16); }

// sorted-ascending 20-slot bubble insert, f32 keys (positive, bit-ordered)
__device__ __forceinline__ void bubble20f(float (&a)[K_], float key) {
    float carry = key;
#pragma unroll
    for (int s = 0; s < K_; ++s) {
        float as = a[s];
        a[s]  = fminf(carry, as);
        carry = fmaxf(carry, as);
    }
}
// key = (dist_bits & ~0xFFF) | cid   (cid < 4096; dist >= 0 finite)
__device__ __forceinline__ float mkkey(float dist, int cid) {
    return __uint_as_float((__float_as_uint(dist) & 0xFFFFF000u) | (u32)cid);
}

// ---------------------------------------------------------------- pack x -> (x,y,z,d2) float4
__global__ __launch_bounds__(256) void pack4_kernel(const float* __restrict__ x,
                                                    float4* __restrict__ xp) {
    int i = blockIdx.x * 256 + threadIdx.x;
    if (i >= NPT) return;
    float ax = x[(size_t)i * 3], ay = x[(size_t)i * 3 + 1], az = x[(size_t)i * 3 + 2];
    xp[i] = make_float4(ax, ay, az, ax * ax + ay * ay + az * az);
}

// ---------------------------------------------------------------- fused d2 + h/m split (D=64)
__global__ __launch_bounds__(256) void d2cvt2_kernel(const float* __restrict__ x,
                                                     float* __restrict__ d2,
                                                     u16* __restrict__ xh,
                                                     u16* __restrict__ xm) {
    int i = blockIdx.x * 256 + threadIdx.x;
    if (i >= NPT) return;
    const float* r = x + (size_t)i * 64;
    float s = 0.f;
#pragma unroll
    for (int d8 = 0; d8 < 64; d8 += 8) {
        float4 v0 = *(const float4*)(r + d8);
        float4 v1 = *(const float4*)(r + d8 + 4);
        s += v0.x * v0.x + v0.y * v0.y + v0.z * v0.z + v0.w * v0.w;
        s += v1.x * v1.x + v1.y * v1.y + v1.z * v1.z + v1.w * v1.w;
        float av[8] = {v0.x, v0.y, v0.z, v0.w, v1.x, v1.y, v1.z, v1.w};
        bf16x8 vh, vm;
#pragma unroll
        for (int j = 0; j < 8; ++j) {
            u16 h = f2bf(av[j]);
            float r1 = av[j] - bf2f(h);
            vh[j] = (short)h; vm[j] = (short)f2bf(r1);
        }
        *(bf16x8*)(xh + (size_t)i * 64 + d8) = vh;
        *(bf16x8*)(xm + (size_t)i * 64 + d8) = vm;
    }
    d2[i] = s;
}

// ---------------------------------------------------------------- layer-1 knn (D=3): 512 threads,
// 2 candidate-half groups, barrier-free scan, in-block two-pointer merge.
__global__ __launch_bounds__(512) void knnf3_kernel(const float4* __restrict__ xp,
                                                    int* __restrict__ idx) {
    __shared__ float sKeys[2][64][21];   // padded stride 21

    int b = blockIdx.y;
    int q0 = blockIdx.x * 64;
    const float4* xb = xp + (size_t)b * P_;

    int t = threadIdx.x, wave = t >> 6, ln = t & 63;
    int g = wave >> 2, w2 = wave & 3;
    int q  = ln & 15;
    int ss = ln >> 4;

    int qrow = q0 + w2 * 16 + q;
    float4 qv = xb[qrow];

    float a[K_];
#pragma unroll
    for (int s = 0; s < K_; ++s)
        a[s] = __uint_as_float(0x7F7FF000u | (u32)s);    // distinct huge finite sentinels
    const float PINV = __uint_as_float(0x7F800000u);     // +inf
    const float BIGF = __uint_as_float(0x7F7FFFFFu);     // FLT_MAX

    float p0 = PINV, p1 = PINV, p2 = PINV, p3 = PINV;
    int pcnt = 0;
    float kthr = BIGF;

    int cbase = g * HALF;
#pragma unroll 1
    for (int c0 = cbase; c0 < cbase + HALF; c0 += 64) {
#pragma unroll
        for (int nt = 0; nt < 4; ++nt) {
            float4 cv[4];
#pragma unroll
            for (int r = 0; r < 4; ++r)
                cv[r] = xb[c0 + nt * 16 + ss * 4 + r];
#pragma unroll
            for (int r = 0; r < 4; ++r) {
                int cID = c0 + nt * 16 + ss * 4 + r;
                float dv = (qv.w + cv[r].w)
                         - 2.f * (qv.x * cv[r].x + qv.y * cv[r].y + qv.z * cv[r].z);
                if (cID == qrow) dv += 1e10f;
                dv = fmaxf(dv, 0.f);
                if (__any(dv <= kthr)) {
                    float key = mkkey(dv, cID);
                    bool pass = key < a[K_ - 1];
                    p3 = pass ? p2 : p3;
                    p2 = pass ? p1 : p2;
                    p1 = pass ? p0 : p1;
                    p0 = pass ? key : p0;
                    pcnt = pass ? pcnt + 1 : pcnt;
                    if (__any(pcnt >= 4)) {
                        bubble20f(a, p3); bubble20f(a, p2); bubble20f(a, p1); bubble20f(a, p0);
                        p0 = p1 = p2 = p3 = PINV; pcnt = 0;
                        kthr = __uint_as_float(__float_as_uint(a[K_ - 1]) | 0xFFFu);
                    }
                }
            }
        }
    }
    bubble20f(a, p3); bubble20f(a, p2); bubble20f(a, p1); bubble20f(a, p0);

    // in-wave 4-substream merge -> sorted per-group keys to LDS
#pragma unroll 1
    for (int k = 0; k < K_; ++k) {
        float v = a[0];
        float v1 = __shfl_xor(v, 16);
        v = fminf(v, v1);
        float v2 = __shfl_xor(v, 32);
        v = fminf(v, v2);
        bool win = (__float_as_uint(a[0]) == __float_as_uint(v));
#pragma unroll
        for (int s = 0; s < K_ - 1; ++s) a[s] = win ? a[s + 1] : a[s];
        a[K_ - 1] = win ? BIGF : a[K_ - 1];
        if (ss == 0) sKeys[g][w2 * 16 + q][k] = v;
    }
    __syncthreads();

    // exact two-pointer merge of the two disjoint-range sorted lists
    if (t < 64) {
        int qq = t;
        int* op = idx + ((size_t)(b * P_ + q0 + qq)) * K_;
        int iA = 0, iB = 0;
#pragma unroll 1
        for (int k = 0; k < K_; ++k) {
            float va = sKeys[0][qq][iA];
            float vb = sKeys[1][qq][iB];
            bool ta = va < vb;                 // keys unique (disjoint cid ranges)
            float v = ta ? va : vb;
            iA += ta ? 1 : 0;
            iB += ta ? 0 : 1;
            op[k] = b * P_ + (int)(__float_as_uint(v) & 0xFFFu);
        }
    }
}

// ---------------------------------------------------------------- fused knn (D=64) via MFMA,
// 3-product h/m; 512 threads, 2 candidate-half groups, twin LDS buffers, in-block merge.
__global__ __launch_bounds__(512) void knnm64_kernel(const u16* __restrict__ xh,
                                                     const u16* __restrict__ xm,
                                                     const float* __restrict__ d2,
                                                     int* __restrict__ idx) {
    __shared__ u16 sH[2][64 * 64];   // 16 KB; elem (r,k) at byte r*128 + ((k*2)^((r&7)<<4))
    __shared__ u16 sM[2][64 * 64];   // 16 KB
    __shared__ float sd2[P_];        // 16 KB
    __shared__ float sKeys[2][64][21];  // 10.5 KB

    int b = blockIdx.y;
    int q0 = blockIdx.x * 64;
    const u16* xhb = xh + (size_t)b * P_ * 64;
    const u16* xmb = xm + (size_t)b * P_ * 64;
    const float* d2b = d2 + (size_t)b * P_;

    int t = threadIdx.x, wave = t >> 6, ln = t & 63;
    int g = wave >> 2, w2 = wave & 3;
    int q  = ln & 15;
    int ss = ln >> 4;

    for (int i = t; i < P_ / 4; i += 512)
        ((float4*)sd2)[i] = ((const float4*)d2b)[i];

    int qrow = q0 + w2 * 16 + q;
    bf16x8 qh[2], qm[2];
#pragma unroll
    for (int kt = 0; kt < 2; ++kt) {
        size_t off = (size_t)qrow * 64 + kt * 32 + ss * 8;
        qh[kt] = *(const bf16x8*)(xhb + off);
        qm[kt] = *(const bf16x8*)(xmb + off);
    }

    __syncthreads();
    float qd2 = sd2[qrow];

    float a[K_];
#pragma unroll
    for (int s = 0; s < K_; ++s)
        a[s] = __uint_as_float(0x7F7FF000u | (u32)s);
    const float PINV = __uint_as_float(0x7F800000u);     // +inf
    const float BIGF = __uint_as_float(0x7F7FFFFFu);     // FLT_MAX

    float p0 = PINV, p1 = PINV, p2 = PINV, p3 = PINV;
    int pcnt = 0;
    float kthr = BIGF;

    // staging: 512 threads cover 128 rows (64 per buffer), 4 threads/row, 16 elems each
    int srow = t >> 2;               // 0..127
    int sbuf = srow >> 6;            // which buffer this thread fills
    int sr = srow & 63;
    int sk2 = (t & 3) * 32;
    int sbase = sr * 128, sswz = (sr & 7) << 4;
    size_t sgof = (size_t)sr * 64 + (t & 3) * 16;

#pragma unroll 1
    for (int it = 0; it < HALF / 64; ++it) {
        int c0A = it * 64;
        int c0B = HALF + it * 64;
        __syncthreads();
        {
            int cc0 = sbuf ? c0B : c0A;
            size_t gaddr = (size_t)cc0 * 64 + sgof;
            bf16x8 h0 = *(const bf16x8*)(xhb + gaddr);
            bf16x8 h1 = *(const bf16x8*)(xhb + gaddr + 8);
            bf16x8 m0 = *(const bf16x8*)(xmb + gaddr);
            bf16x8 m1 = *(const bf16x8*)(xmb + gaddr + 8);
            *(bf16x8*)((char*)sH[sbuf] + sbase + (sk2 ^ sswz)) = h0;
            *(bf16x8*)((char*)sH[sbuf] + sbase + ((sk2 + 16) ^ sswz)) = h1;
            *(bf16x8*)((char*)sM[sbuf] + sbase + (sk2 ^ sswz)) = m0;
            *(bf16x8*)((char*)sM[sbuf] + sbase + ((sk2 + 16) ^ sswz)) = m1;
        }
        __syncthreads();

        int cg = g ? c0B : c0A;
        const char* bH = (const char*)sH[g];
        const char* bM = (const char*)sM[g];

        f32x4 acc[4];
#pragma unroll
        for (int nt = 0; nt < 4; ++nt) {
            acc[nt] = (f32x4){0.f, 0.f, 0.f, 0.f};
            int r = nt * 16 + q;
            int base = r * 128, swz = (r & 7) << 4;
#pragma unroll
            for (int kt = 0; kt < 2; ++kt) {
                int k2 = kt * 64 + ss * 16;
                bf16x8 ch = *(const bf16x8*)(bH + base + (k2 ^ swz));
                bf16x8 cm = *(const bf16x8*)(bM + base + (k2 ^ swz));
                // 3-product split: hh + hm + mh
                acc[nt] = __builtin_amdgcn_mfma_f32_16x16x32_bf16(cm, qh[kt], acc[nt], 0, 0, 0);
                acc[nt] = __builtin_amdgcn_mfma_f32_16x16x32_bf16(ch, qm[kt], acc[nt], 0, 0, 0);
                acc[nt] = __builtin_amdgcn_mfma_f32_16x16x32_bf16(ch, qh[kt], acc[nt], 0, 0, 0);
            }
        }

        float dvv[4][4];
        float mn = 3.4e38f;
#pragma unroll
        for (int nt = 0; nt < 4; ++nt) {
#pragma unroll
            for (int r = 0; r < 4; ++r) {
                int cID = cg + nt * 16 + ss * 4 + r;
                float dv = (qd2 + sd2[cID]) - 2.f * acc[nt][r];
                if (cID == qrow) dv += 1e10f;
                dv = fmaxf(dv, 0.f);
                dvv[nt][r] = dv;
                mn = fminf(mn, dv);
            }
        }
        if (__any(mn <= kthr)) {
#pragma unroll
            for (int nt = 0; nt < 4; ++nt) {
#pragma unroll
                for (int r = 0; r < 4; ++r) {
                    float dv = dvv[nt][r];
                    if (__any(dv <= kthr)) {
                        float key = mkkey(dv, cg + nt * 16 + ss * 4 + r);
                        bool pass = key < a[K_ - 1];
                        p3 = pass ? p2 : p3;
                        p2 = pass ? p1 : p2;
                        p1 = pass ? p0 : p1;
                        p0 = pass ? key : p0;
                        pcnt = pass ? pcnt + 1 : pcnt;
                        if (__any(pcnt >= 4)) {
                            bubble20f(a, p3); bubble20f(a, p2); bubble20f(a, p1); bubble20f(a, p0);
                            p0 = p1 = p2 = p3 = PINV; pcnt = 0;
                            kthr = __uint_as_float(__float_as_uint(a[K_ - 1]) | 0xFFFu);
                        }
                    }
                }
            }
        }
    }
    bubble20f(a, p3); bubble20f(a, p2); bubble20f(a, p1); bubble20f(a, p0);

    // in-wave 4-substream merge -> sorted per-group keys to LDS
#pragma unroll 1
    for (int k = 0; k < K_; ++k) {
        float v = a[0];
        float v1 = __shfl_xor(v, 16);
        v = fminf(v, v1);
        float v2 = __shfl_xor(v, 32);
        v = fminf(v, v2);
        bool win = (__float_as_uint(a[0]) == __float_as_uint(v));
#pragma unroll
        for (int s = 0; s < K_ - 1; ++s) a[s] = win ? a[s + 1] : a[s];
        a[K_ - 1] = win ? BIGF : a[K_ - 1];
        if (ss == 0) sKeys[g][w2 * 16 + q][k] = v;
    }
    __syncthreads();

    // exact two-pointer merge of the two disjoint-range sorted lists
    if (t < 64) {
        int qq = t;
        int* op = idx + ((size_t)(b * P_ + q0 + qq)) * K_;
        int iA = 0, iB = 0;
#pragma unroll 1
        for (int k = 0; k < K_; ++k) {
            float va = sKeys[0][qq][iA];
            float vb = sKeys[1][qq][iB];
            bool ta = va < vb;
            float v = ta ? va : vb;
            iA += ta ? 1 : 0;
            iB += ta ? 0 : 1;
            op[k] = b * P_ + (int)(__float_as_uint(v) & 0xFFFu);
        }
    }
}

// ---------------------------------------------------------------- one-shot weight prep
__global__ __launch_bounds__(256) void prep_kernel(const float* __restrict__ W2,
                                                   const float* __restrict__ b2,
                                                   const float* __restrict__ W3,
                                                   const float* __restrict__ b3,
                                                   const float* __restrict__ Wl,
                                                   const float* __restrict__ Wm1,
                                                   const float* __restrict__ Wm2,
                                                   float* __restrict__ Wpk2, float* __restrict__ bpk2,
                                                   float* __restrict__ Wpk3, float* __restrict__ bpk3,
                                                   u16* __restrict__ WlT,
                                                   u16* __restrict__ Wm1T,
                                                   u16* __restrict__ Wm2T) {
    int t = blockIdx.x * 256 + threadIdx.x;
    if (t < 8192) {
        int d = t >> 7, h2 = t & 127;
        Wpk2[t] = (h2 < 64) ? W2[d * 64 + h2] : W2[(64 + d) * 64 + (h2 - 64)];
        if (t < 128) bpk2[t] = (t < 64) ? b2[t] : 0.f;
    } else if (t < 16384) {
        int t2 = t - 8192;
        int d = t2 >> 7, h2 = t2 & 127;
        Wpk3[t2] = (h2 < 64) ? W3[d * 64 + h2] : W3[(64 + d) * 64 + (h2 - 64)];
        if (t2 < 128) bpk3[t2] = (t2 < 64) ? b3[t2] : 0.f;
    } else if (t < 212992) {
        int t2 = t - 16384;
        int k = t2 >> 10, n = t2 & 1023;
        WlT[(size_t)n * 192 + k] = f2bf(Wl[t2]);
    } else if (t < 475136) {
        int t2 = t - 212992;
        int k = t2 >> 8, n = t2 & 255;
        Wm1T[(size_t)n * 1024 + k] = f2bf(Wm1[t2]);
    } else if (t < 507904) {
        int t2 = t - 475136;
        int k = t2 >> 7, n = t2 & 127;
        Wm2T[(size_t)n * 256 + k] = f2bf(Wm2[t2]);
    }
}

// ---------------------------------------------------------------- layer-1 UV (D=3, direct)
__global__ __launch_bounds__(256) void uv3_kernel(const float* __restrict__ x,
                                                  const float* __restrict__ W,
                                                  const float* __restrict__ b,
                                                  float* __restrict__ UV) {
    int t = blockIdx.x * 256 + threadIdx.x;
    int p = t >> 7, h2 = t & 127;
    float x0 = x[p * 3], x1 = x[p * 3 + 1], x2 = x[p * 3 + 2];
    float r;
    if (h2 < 64) {
        r = b[h2] + x0 * W[h2] + x1 * W[64 + h2] + x2 * W[128 + h2];
    } else {
        int h = h2 - 64;
        r = x0 * W[192 + h] + x1 * W[256 + h] + x2 * W[320 + h];
    }
    UV[t] = r;
}

// ---------------------------------------------------------------- edge max
__global__ __launch_bounds__(256) void edgemax_kernel(const float* __restrict__ UV,
                                                      const int* __restrict__ idx,
                                                      float* __restrict__ xout) {
    int wv = threadIdx.x >> 6, lane = threadIdx.x & 63;
    int p = blockIdx.x * 4 + wv;
    const float* uvp = UV + (size_t)p * 128;
    float duv = uvp[lane] - uvp[64 + lane];
    const int* ip = idx + (size_t)p * K_;
    int jj[K_];
#pragma unroll
    for (int k = 0; k < K_; ++k) jj[k] = ip[k];
    float m = -3.4e38f;
#pragma unroll
    for (int k = 0; k < K_; ++k) {
        float vj = UV[(size_t)jj[k] * 128 + 64 + lane];
        float t = duv + vj;
        m = fmaxf(m, fmaxf(t, NEG_SLOPE * t));
    }
    xout[(size_t)p * H_ + lane] = m;
}

// ---------------------------------------------------------------- GEMM 64x64 f32 (UV)
__global__ __launch_bounds__(256) void gemm_kernel(const float* __restrict__ A1,
                                                   const float* __restrict__ Wm,
                                                   const float* __restrict__ bias,
                                                   float* __restrict__ Cm,
                                                   int M, int N, int Kd, int leaky) {
    __shared__ float sA[32][68];
    __shared__ float sB[32][68];

    int tid = threadIdx.x;
    int row0 = blockIdx.x * 64, col0 = blockIdx.y * 64;
    int tx = tid & 15, ty = tid >> 4;

    int lr  = tid >> 2;
    int lk4 = (tid & 3) * 4;
    int lkb = tid >> 4;
    int lnb = (tid & 15) * 4;

    float acc[4][4] = {};

    for (int k0 = 0; k0 < Kd; k0 += 32) {
        int arow = row0 + lr;
#pragma unroll
        for (int h = 0; h < 32; h += 16) {
            int kk = k0 + lk4 + h;
            const float* src = A1 + (size_t)arow * Kd + kk;
            float4 av = *(const float4*)src;
            sA[lk4 + h + 0][lr] = av.x; sA[lk4 + h + 1][lr] = av.y;
            sA[lk4 + h + 2][lr] = av.z; sA[lk4 + h + 3][lr] = av.w;
        }
        int bcol = col0 + lnb;
#pragma unroll
        for (int h = 0; h < 32; h += 16) {
            float4 bv = make_float4(0.f, 0.f, 0.f, 0.f);
            if (bcol < N) bv = *(const float4*)(Wm + (size_t)(k0 + lkb + h) * N + bcol);
            *(float4*)&sB[lkb + h][lnb] = bv;
        }
        __syncthreads();

#pragma unroll
        for (int kk2 = 0; kk2 < 32; ++kk2) {
            float4 a = *(const float4*)&sA[kk2][ty * 4];
            float4 bb = *(const float4*)&sB[kk2][tx * 4];
            acc[0][0] = fmaf(a.x, bb.x, acc[0][0]); acc[0][1] = fmaf(a.x, bb.y, acc[0][1]);
            acc[0][2] = fmaf(a.x, bb.z, acc[0][2]); acc[0][3] = fmaf(a.x, bb.w, acc[0][3]);
            acc[1][0] = fmaf(a.y, bb.x, acc[1][0]); acc[1][1] = fmaf(a.y, bb.y, acc[1][1]);
            acc[1][2] = fmaf(a.y, bb.z, acc[1][2]); acc[1][3] = fmaf(a.y, bb.w, acc[1][3]);
            acc[2][0] = fmaf(a.z, bb.x, acc[2][0]); acc[2][1] = fmaf(a.z, bb.y, acc[2][1]);
            acc[2][2] = fmaf(a.z, bb.z, acc[2][2]); acc[2][3] = fmaf(a.z, bb.w, acc[2][3]);
            acc[3][0] = fmaf(a.w, bb.x, acc[3][0]); acc[3][1] = fmaf(a.w, bb.y, acc[3][1]);
            acc[3][2] = fmaf(a.w, bb.z, acc[3][2]); acc[3][3] = fmaf(a.w, bb.w, acc[3][3]);
        }
        __syncthreads();
    }

    for (int i = 0; i < 4; ++i) {
        int row = row0 + ty * 4 + i;
        for (int j = 0; j < 4; ++j) {
            int col = col0 + tx * 4 + j;
            if (col < N) {
                float v = acc[i][j] + bias[col];
                if (leaky) v = v > 0.f ? v : NEG_SLOPE * v;
                Cm[(size_t)row * N + col] = v;
            }
        }
    }
}

// ---------------------------------------------------------------- MFMA GEMM head (bf16 A)
template <int KD, int OUT_BF16>
__global__ __launch_bounds__(256) void gemm_mfma_kernel(const u16* __restrict__ A,
                                                        const u16* __restrict__ BT,
                                                        const float* __restrict__ bias,
                                                        void* __restrict__ Cout,
                                                        int N, int leaky) {
    __shared__ u16 sA[128 * 64];
    __shared__ u16 sB[128 * 64];

    int t = threadIdx.x;
    int wave = t >> 6, lane = t & 63;
    int wm = wave >> 1, wn = wave & 1;
    int row0 = blockIdx.x * 128;
    int col0 = blockIdx.y * 128;

    f32x4 acc[4][4] = {};

    for (int k0 = 0; k0 < KD; k0 += 64) {
        __syncthreads();
#pragma unroll
        for (int i = 0; i < 4; ++i) {
            int li = t + i * 256;
            int r = li >> 3;
            int kc = (li & 7) * 8;
            bf16x8 v = *(const bf16x8*)(A + (size_t)(row0 + r) * KD + k0 + kc);
            *(bf16x8*)((char*)sA + r * 128 + ((kc * 2) ^ ((r & 7) << 4))) = v;
        }
#pragma unroll
        for (int i = 0; i < 4; ++i) {
            int li = t + i * 256;
            int n = li >> 3;
            int kc = (li & 7) * 8;
            bf16x8 v = *(const bf16x8*)(BT + (size_t)(col0 + n) * KD + k0 + kc);
            *(bf16x8*)((char*)sB + n * 128 + ((kc * 2) ^ ((n & 7) << 4))) = v;
        }
        __syncthreads();

#pragma unroll
        for (int kk = 0; kk < 2; ++kk) {
            int kb = kk * 64 + (lane >> 4) * 16;
            bf16x8 af[4], bfr[4];
#pragma unroll
            for (int mi = 0; mi < 4; ++mi) {
                int r = wm * 64 + mi * 16 + (lane & 15);
                af[mi] = *(const bf16x8*)((char*)sA + r * 128 + (kb ^ ((r & 7) << 4)));
            }
#pragma unroll
            for (int ni = 0; ni < 4; ++ni) {
                int n = wn * 64 + ni * 16 + (lane & 15);
                bfr[ni] = *(const bf16x8*)((char*)sB + n * 128 + (kb ^ ((n & 7) << 4)));
            }
#pragma unroll
            for (int mi = 0; mi < 4; ++mi)
#pragma unroll
                for (int ni = 0; ni < 4; ++ni)
                    acc[mi][ni] = __builtin_amdgcn_mfma_f32_16x16x32_bf16(
                        af[mi], bfr[ni], acc[mi][ni], 0, 0, 0);
        }
    }

#pragma unroll
    for (int ni = 0; ni < 4; ++ni) {
        int col = col0 + wn * 64 + ni * 16 + (lane & 15);
        float bs = bias[col];
#pragma unroll
        for (int mi = 0; mi < 4; ++mi) {
#pragma unroll
            for (int r = 0; r < 4; ++r) {
                int row = row0 + wm * 64 + mi * 16 + (lane >> 4) * 4 + r;
                float v = acc[mi][ni][r] + bs;
                if (leaky) v = v > 0.f ? v : NEG_SLOPE * v;
                if (OUT_BF16)
                    ((u16*)Cout)[(size_t)row * N + col] = f2bf(v);
                else
                    ((float*)Cout)[(size_t)row * N + col] = v;
            }
        }
    }
}

// ---------------------------------------------------------------- MFMA GEMM, cat-f32 A (fused cvt)
__global__ __launch_bounds__(256) void gemm_mfma_cat_kernel(const float* __restrict__ x1,
                                                            const float* __restrict__ x2,
                                                            const float* __restrict__ x3,
                                                            const u16* __restrict__ BT,
                                                            const float* __restrict__ bias,
                                                            u16* __restrict__ Cout,
                                                            int N) {
    __shared__ u16 sA[128 * 64];
    __shared__ u16 sB[128 * 64];

    int t = threadIdx.x;
    int wave = t >> 6, lane = t & 63;
    int wm = wave >> 1, wn = wave & 1;
    int row0 = blockIdx.x * 128;
    int col0 = blockIdx.y * 128;

    f32x4 acc[4][4] = {};

#pragma unroll 1
    for (int k0 = 0; k0 < 192; k0 += 64) {
        const float* src = (k0 == 0) ? x1 : (k0 == 64) ? x2 : x3;
        __syncthreads();
#pragma unroll
        for (int i = 0; i < 4; ++i) {
            int li = t + i * 256;
            int r = li >> 3;
            int kc = (li & 7) * 8;
            const float* sp = src + (size_t)(row0 + r) * 64 + kc;
            float4 a0 = *(const float4*)sp;
            float4 a1 = *(const float4*)(sp + 4);
            bf16x8 v;
            v[0] = (short)f2bf(a0.x); v[1] = (short)f2bf(a0.y);
            v[2] = (short)f2bf(a0.z); v[3] = (short)f2bf(a0.w);
            v[4] = (short)f2bf(a1.x); v[5] = (short)f2bf(a1.y);
            v[6] = (short)f2bf(a1.z); v[7] = (short)f2bf(a1.w);
            *(bf16x8*)((char*)sA + r * 128 + ((kc * 2) ^ ((r & 7) << 4))) = v;
        }
#pragma unroll
        for (int i = 0; i < 4; ++i) {
            int li = t + i * 256;
            int n = li >> 3;
            int kc = (li & 7) * 8;
            bf16x8 v = *(const bf16x8*)(BT + (size_t)(col0 + n) * 192 + k0 + kc);
            *(bf16x8*)((char*)sB + n * 128 + ((kc * 2) ^ ((n & 7) << 4))) = v;
        }
        __syncthreads();

#pragma unroll
        for (int kk = 0; kk < 2; ++kk) {
            int kb = kk * 64 + (lane >> 4) * 16;
            bf16x8 af[4], bfr[4];
#pragma unroll
            for (int mi = 0; mi < 4; ++mi) {
                int r = wm * 64 + mi * 16 + (lane & 15);
                af[mi] = *(const bf16x8*)((char*)sA + r * 128 + (kb ^ ((r & 7) << 4)));
            }
#pragma unroll
            for (int ni = 0; ni < 4; ++ni) {
                int n = wn * 64 + ni * 16 + (lane & 15);
                bfr[ni] = *(const bf16x8*)((char*)sB + n * 128 + (kb ^ ((n & 7) << 4)));
            }
#pragma unroll
            for (int mi = 0; mi < 4; ++mi)
#pragma unroll
                for (int ni = 0; ni < 4; ++ni)
                    acc[mi][ni] = __builtin_amdgcn_mfma_f32_16x16x32_bf16(
                        af[mi], bfr[ni], acc[mi][ni], 0, 0, 0);
        }
    }

#pragma unroll
    for (int ni = 0; ni < 4; ++ni) {
        int col = col0 + wn * 64 + ni * 16 + (lane & 15);
        float bs = bias[col];
#pragma unroll
        for (int mi = 0; mi < 4; ++mi) {
#pragma unroll
            for (int r = 0; r < 4; ++r) {
                int row = row0 + wm * 64 + mi * 16 + (lane >> 4) * 4 + r;
                float v = acc[mi][ni][r] + bs;
                v = v > 0.f ? v : NEG_SLOPE * v;
                Cout[(size_t)row * N + col] = f2bf(v);
            }
        }
    }
}

// ---------------------------------------------------------------- fused Wo GEMM + log_softmax
__global__ __launch_bounds__(256) void lsm_wo_kernel(const float* __restrict__ act3,
                                                     const float* __restrict__ Wo,
                                                     const float* __restrict__ bo,
                                                     float* __restrict__ out) {
    __shared__ float sWo[128 * 44];
    __shared__ float sAct[4][128];

    int t = threadIdx.x;
    for (int i = t; i < 128 * 40; i += 256) {
        int k = i / 40, c = i % 40;
        sWo[k * 44 + c] = Wo[i];
    }
    __syncthreads();

    int wv = t >> 6, lane = t & 63;
    int row = blockIdx.x * 4 + wv;
    sAct[wv][lane]      = act3[(size_t)row * 128 + lane];
    sAct[wv][64 + lane] = act3[(size_t)row * 128 + 64 + lane];

    float acc = (lane < C_) ? bo[lane] : -3.4e38f;
    if (lane < C_) {
#pragma unroll 8
        for (int k = 0; k < 128; ++k)
            acc = fmaf(sAct[wv][k], sWo[k * 44 + lane], acc);
    }
    float m = acc;
#pragma unroll
    for (int s = 1; s < 64; s <<= 1) m = fmaxf(m, __shfl_xor(m, s));
    float e = (lane < C_) ? expf(acc - m) : 0.f;
    float sum = e;
#pragma unroll
    for (int s = 1; s < 64; s <<= 1) sum += __shfl_xor(sum, s);
    if (lane < C_) out[(size_t)row * C_ + lane] = acc - m - logf(sum);
}

// ----------------------------------------------------------------
extern "C" void kernel_launch(void* const* d_in, const int* in_sizes, int n_in,
                              void* d_out, int out_size, void* d_ws, size_t ws_size,
                              hipStream_t stream) {
    const float* x   = (const float*)d_in[0];
    const float* W1  = (const float*)d_in[2];
    const float* b1  = (const float*)d_in[3];
    const float* W2  = (const float*)d_in[4];
    const float* b2  = (const float*)d_in[5];
    const float* W3  = (const float*)d_in[6];
    const float* b3  = (const float*)d_in[7];
    const float* Wl  = (const float*)d_in[8];
    const float* bl  = (const float*)d_in[9];
    const float* Wm1 = (const float*)d_in[10];
    const float* bm1 = (const float*)d_in[11];
    const float* Wm2 = (const float*)d_in[12];
    const float* bm2 = (const float*)d_in[13];
    const float* Wo  = (const float*)d_in[14];
    const float* bo  = (const float*)d_in[15];
    float* out = (float*)d_out;

    // ---- workspace (max 50,987,008 B — proven footprint) ----
    char* ws = (char*)d_ws;
    float* x1   = (float*)(ws);
    float* x2   = (float*)(ws + 8388608);
    float* x3   = (float*)(ws + 16777216);
    int*   idx  = (int*)  (ws + 25165824);
    float* d2   = (float*)(ws + 27787264);
    char* hb = ws + 27918336;
    float4* xp  = (float4*)(hb);                      // 512 KB (layer-1 knn; dead before UV)
    u16*   xhs  = (u16*)(hb);                         // 4 MB (layer-2/3 knn)
    u16*   xms  = (u16*)(hb + 4194304);               // 4 MB
    float* UV   = (float*)(hb);                       // 16 MB (edge phase)
    float* Wpk2 = (float*)(ws + 44695552);
    float* bpk2 = (float*)(ws + 44728320);
    float* Wpk3 = (float*)(ws + 44728832);
    float* bpk3 = (float*)(ws + 44761600);
    u16*   WlT  = (u16*)  (ws + 44762112);
    u16*   Wm1T = (u16*)  (ws + 45155328);
    u16*   Wm2T = (u16*)  (ws + 45679616);
    u16*   act1 = (u16*)(hb);
    u16*   act2 = (u16*)(ws + 45745152);
    float* act3 = (float*)(hb);

    prep_kernel<<<1984, 256, 0, stream>>>(W2, b2, W3, b3, Wl, Wm1, Wm2,
                                          Wpk2, bpk2, Wpk3, bpk3, WlT, Wm1T, Wm2T);

    // ---- layer 1 (D=3): barrier-free split knn on packed xp
    pack4_kernel<<<NPT / 256, 256, 0, stream>>>(x, xp);
    knnf3_kernel<<<dim3(P_ / 64, B_), 512, 0, stream>>>(xp, idx);
    uv3_kernel<<<NPT * 128 / 256, 256, 0, stream>>>(x, W1, b1, UV);
    edgemax_kernel<<<NPT / 4, 256, 0, stream>>>(UV, idx, x1);
    // ---- layer 2 (D=64)
    d2cvt2_kernel<<<NPT / 256, 256, 0, stream>>>(x1, d2, xhs, xms);
    knnm64_kernel<<<dim3(P_ / 64, B_), 512, 0, stream>>>(xhs, xms, d2, idx);
    gemm_kernel<<<dim3(NPT / 64, 2), 256, 0, stream>>>(x1, Wpk2, bpk2, UV, NPT, 128, 64, 0);
    edgemax_kernel<<<NPT / 4, 256, 0, stream>>>(UV, idx, x2);
    // ---- layer 3 (D=64)
    d2cvt2_kernel<<<NPT / 256, 256, 0, stream>>>(x2, d2, xhs, xms);
    knnm64_kernel<<<dim3(P_ / 64, B_), 512, 0, stream>>>(xhs, xms, d2, idx);
    gemm_kernel<<<dim3(NPT / 64, 2), 256, 0, stream>>>(x2, Wpk3, bpk3, UV, NPT, 128, 64, 0);
    edgemax_kernel<<<NPT / 4, 256, 0, stream>>>(UV, idx, x3);

    // ---- MLP head: 4 chunks of 8192 rows
    for (int c = 0; c < 4; ++c) {
        size_t r0 = (size_t)c * 8192;
        gemm_mfma_cat_kernel<<<dim3(64, 8), 256, 0, stream>>>(x1 + r0 * 64, x2 + r0 * 64,
                                                              x3 + r0 * 64, WlT, bl, act1, 1024);
        gemm_mfma_kernel<1024, 1><<<dim3(64, 2), 256, 0, stream>>>(act1, Wm1T, bm1, act2, 256, 1);
        gemm_mfma_kernel<256, 0><<<dim3(64, 1), 256, 0, stream>>>(act2, Wm2T, bm2, act3, 128, 1);
        lsm_wo_kernel<<<2048, 256, 0, stream>>>(act3, Wo, bo, out + r0 * C_);
    }
}